// Round 1
// baseline (1565.663 us; speedup 1.0000x reference)
//
#include <hip/hip_runtime.h>
#include <math.h>

#define D_DIM 1024
#define M_DIM 256
#define B_IMG 64
#define N_TOK 512
#define BN    32768

typedef unsigned short u16;
typedef __attribute__((ext_vector_type(8))) __bf16 bf16x8;
typedef __attribute__((ext_vector_type(4))) float  f32x4;

__device__ __forceinline__ u16 f2bf(float f) {
  union { float f; unsigned u; } c; c.f = f;
  unsigned u = c.u;
  return (u16)((u + 0x7FFFu + ((u >> 16) & 1u)) >> 16);
}
__device__ __forceinline__ float bf2f(u16 h) {
  union { unsigned u; float f; } c; c.u = ((unsigned)h) << 16;
  return c.f;
}

// ---------------------------------------------------------------------------
// Input-dtype detector. flag: 0 = inputs are bf16, 1 = inputs are f32.
// ---------------------------------------------------------------------------
__global__ __launch_bounds__(64) void detect_dtype(const u16* __restrict__ p, int* __restrict__ dflag)
{
  const int lane = threadIdx.x;
  const float a = fabsf(bf2f(p[lane * 2]));
  const bool sane = (a >= 1e-20f && a <= 1e3f);
  const unsigned long long m = __ballot(sane);
  if (lane == 0) *dflag = (m == ~0ull) ? 0 : 1;
}

__device__ __forceinline__ float load_in(const void* p, size_t i, int f) {
  return f ? ((const float*)p)[i] : bf2f(((const u16*)p)[i]);
}

// ---------------------------------------------------------------------------
// OLD 128x128 multi-pass GEMM — kept for small shapes (k, v: R=256).
// EPI: 0 bf16, 1 f32, 2 res+hi/lo, 3 bf16 transposed, 4 hi/lo split.
// ---------------------------------------------------------------------------
template<int EPI>
__global__ __launch_bounds__(256) void gemm_bt(
    const u16* __restrict__ X0, const u16* __restrict__ X1, const u16* __restrict__ X2,
    const u16* __restrict__ Bt0, const u16* __restrict__ Bt1, const u16* __restrict__ Bt2,
    const void* __restrict__ bias, const int* __restrict__ dflag,
    int np_base, int np_extra,
    const u16* res_hi, const u16* res_lo,
    float* outf, u16* outb, u16* outb2,
    int R, int K, int NC)
{
  __shared__ u16 lA[128 * 64];
  __shared__ u16 lB[128 * 64];
  const int tid  = threadIdx.x;
  const int wave = tid >> 6, lane = tid & 63;
  const int quad = lane >> 4, l15 = lane & 15;
  const int wr = wave & 1, wc = wave >> 1;
  const int rblk = blockIdx.x, cblk = blockIdx.y;

  const int np = np_base + (np_extra ? np_extra * (*dflag) : 0);

  const int srow = lane >> 3;
  const int scol = ((lane & 7) ^ (srow & 7)) * 8;

  const u16* Xs[3] = {X0, X1, X2};
  const u16* Bs[3] = {Bt0, Bt1, Bt2};

  f32x4 acc[4][4] = {};

  for (int p = 0; p < np; ++p) {
    const u16* gA = Xs[p] + (size_t)(rblk * 128 + srow) * K + scol;
    const u16* gB = Bs[p] + (size_t)(cblk * 128 + srow) * K + scol;
    for (int k0 = 0; k0 < K; k0 += 64) {
#pragma unroll
      for (int i = 0; i < 4; ++i) {
        const int j = i * 4 + wave;
        __builtin_amdgcn_global_load_lds(
            (const __attribute__((address_space(1))) void*)(gA + (size_t)j * 8 * K + k0),
            (__attribute__((address_space(3))) void*)(lA + j * 512), 16, 0, 0);
        __builtin_amdgcn_global_load_lds(
            (const __attribute__((address_space(1))) void*)(gB + (size_t)j * 8 * K + k0),
            (__attribute__((address_space(3))) void*)(lB + j * 512), 16, 0, 0);
      }
      __syncthreads();
#pragma unroll
      for (int s = 0; s < 2; ++s) {
        bf16x8 af[4], bfr[4];
#pragma unroll
        for (int r = 0; r < 4; ++r) {
          const int row  = wr * 64 + r * 16 + l15;
          const int slot = (s * 4 + quad) ^ (row & 7);
          af[r] = *(const bf16x8*)(lA + row * 64 + slot * 8);
        }
#pragma unroll
        for (int c = 0; c < 4; ++c) {
          const int row  = wc * 64 + c * 16 + l15;
          const int slot = (s * 4 + quad) ^ (row & 7);
          bfr[c] = *(const bf16x8*)(lB + row * 64 + slot * 8);
        }
#pragma unroll
        for (int r = 0; r < 4; ++r)
#pragma unroll
          for (int c = 0; c < 4; ++c)
            acc[r][c] = __builtin_amdgcn_mfma_f32_16x16x32_bf16(af[r], bfr[c], acc[r][c], 0, 0, 0);
      }
      __syncthreads();
    }
  }

  const int fdt = bias ? *dflag : 0;
  const int crow0 = rblk * 128 + wr * 64;
  const int ccol0 = cblk * 128 + wc * 64;
#pragma unroll
  for (int c = 0; c < 4; ++c) {
    const int col = ccol0 + c * 16 + l15;
    const float bcol = bias ? load_in(bias, col, fdt) : 0.0f;
#pragma unroll
    for (int r = 0; r < 4; ++r) {
#pragma unroll
      for (int t = 0; t < 4; ++t) {
        const int row = crow0 + r * 16 + quad * 4 + t;
        const size_t idx = (size_t)row * NC + col;
        float v = acc[r][c][t] + bcol;
        if (EPI == 0) {
          outb[idx] = f2bf(v);
        } else if (EPI == 1) {
          outf[idx] = v;
        } else if (EPI == 2) {
          const float p = bf2f(res_hi[idx]) + bf2f(res_lo[idx]) + v;
          const u16 hi = f2bf(p);
          outb[idx]  = hi;
          outb2[idx] = f2bf(p - bf2f(hi));
        } else if (EPI == 3) {
          outb[(size_t)col * R + row] = f2bf(v);
        } else {  // EPI 4: hi/lo split
          const u16 hi = f2bf(v);
          outb[idx]  = hi;
          outb2[idx] = f2bf(v - bf2f(hi));
        }
      }
    }
  }
}

// ---------------------------------------------------------------------------
// NEW 256x256-tile GEMM, 8 waves (2M x 4N), BK=64, double-buffered 128 KiB
// LDS, counted-vmcnt 2-deep pipeline (T4): stage tile t+2 right after the
// reads of buf[t&1] finish; wait vmcnt(8) = only tile t+1's 8 loads, which
// were issued a full compute-tile earlier. Never drains vmcnt to 0 in the
// steady-state loop. Fragment/LDS swizzle mapping identical to gemm_bt
// (0 bank conflicts measured). Same multi-pass semantics as gemm_bt.
// EPI: 0 bf16, 1 f32, 2 res+hi/lo, 4 hi/lo split.
// Requires: R % 256 == 0, NC % 256 == 0, K % 64 == 0, K power-of-2 tiles.
// ---------------------------------------------------------------------------
template<int EPI>
__global__ __launch_bounds__(512, 2) void gemm256(
    const u16* __restrict__ X0, const u16* __restrict__ X1, const u16* __restrict__ X2,
    const u16* __restrict__ Bt0, const u16* __restrict__ Bt1, const u16* __restrict__ Bt2,
    const void* __restrict__ bias, const int* __restrict__ dflag,
    int np_base, int np_extra,
    const u16* res_hi, const u16* res_lo,
    float* outf, u16* outb, u16* outb2,
    int R, int K, int NC)
{
  extern __shared__ u16 lds2[];   // [2 bufs][A 256x64 | B 256x64] = 128 KiB
  const int tid  = threadIdx.x;
  const int wave = tid >> 6, lane = tid & 63;
  const int quad = lane >> 4, l15 = lane & 15;
  const int wm = wave >> 2, wn = wave & 3;     // 2x4 wave grid
  const int rblk = blockIdx.x, cblk = blockIdx.y;

  const int np = np_base + (np_extra ? np_extra * (*dflag) : 0);
  const int ktiles = K >> 6;                    // K-tiles per pass (pow2)
  const int ktl = 31 - __builtin_clz(ktiles);
  const int NT = np << ktl;                     // total K-tiles (>= 4 here)

  const u16* Xs[3] = {X0, X1, X2};
  const u16* Bs[3] = {Bt0, Bt1, Bt2};

  // staging geometry: per gload, a wave covers 8 rows; lane -> row lane>>3,
  // source col-slot XOR-swizzled so read slot = kb ^ (row&7) is conflict-free.
  const int srow = lane >> 3;
  const int scol = ((lane & 7) ^ srow) * 8;

  f32x4 acc[8][4] = {};

  auto stage = [&](int t) {
    const int p  = t >> ktl;
    const int k0 = (t & (ktiles - 1)) << 6;
    const u16* gA = Xs[p] + (size_t)(rblk * 256 + srow) * K + k0 + scol;
    const u16* gB = Bs[p] + (size_t)(cblk * 256 + srow) * K + k0 + scol;
    u16* dst = lds2 + (t & 1) * 32768;
#pragma unroll
    for (int i = 0; i < 4; ++i) {
      const int r0 = i * 64 + wave * 8;
      __builtin_amdgcn_global_load_lds(
          (const __attribute__((address_space(1))) void*)(gA + (size_t)r0 * K),
          (__attribute__((address_space(3))) void*)(dst + r0 * 64), 16, 0, 0);
      __builtin_amdgcn_global_load_lds(
          (const __attribute__((address_space(1))) void*)(gB + (size_t)r0 * K),
          (__attribute__((address_space(3))) void*)(dst + 16384 + r0 * 64), 16, 0, 0);
    }
  };

  // prologue: 2 tiles in flight; confirm tile 0 only (8 newest stay in flight)
  stage(0);
  stage(1);
  asm volatile("s_waitcnt vmcnt(8)" ::: "memory");
  asm volatile("s_barrier" ::: "memory");

  for (int t = 0; t < NT; ++t) {
    const u16* bufA = lds2 + (t & 1) * 32768;
    const u16* bufB = bufA + 16384;
    __builtin_amdgcn_s_setprio(1);
#pragma unroll
    for (int kk = 0; kk < 2; ++kk) {
      bf16x8 bfr[4];
#pragma unroll
      for (int n = 0; n < 4; ++n) {
        const int row  = wn * 64 + n * 16 + l15;
        const int slot = (kk * 4 + quad) ^ (row & 7);
        bfr[n] = *(const bf16x8*)(bufB + row * 64 + slot * 8);
      }
#pragma unroll
      for (int m = 0; m < 8; ++m) {
        const int row  = wm * 128 + m * 16 + l15;
        const int slot = (kk * 4 + quad) ^ (row & 7);
        const bf16x8 a = *(const bf16x8*)(bufA + row * 64 + slot * 8);
#pragma unroll
        for (int n = 0; n < 4; ++n)
          acc[m][n] = __builtin_amdgcn_mfma_f32_16x16x32_bf16(a, bfr[n], acc[m][n], 0, 0, 0);
      }
    }
    __builtin_amdgcn_s_setprio(0);
    // all waves done reading buf[t&1] before it is restaged
    asm volatile("s_barrier" ::: "memory");
    if (t + 2 < NT) {
      stage(t + 2);                                      // into buf[t&1]
      asm volatile("s_waitcnt vmcnt(8)" ::: "memory");   // tile t+1 landed
      asm volatile("s_barrier" ::: "memory");
    } else if (t + 1 < NT) {
      asm volatile("s_waitcnt vmcnt(0)" ::: "memory");   // drain: last tile
      asm volatile("s_barrier" ::: "memory");
    }
  }

  const int fdt = bias ? *dflag : 0;
  const int crow0 = rblk * 256 + wm * 128;
  const int ccol0 = cblk * 256 + wn * 64;
#pragma unroll
  for (int n = 0; n < 4; ++n) {
    const int col = ccol0 + n * 16 + l15;
    const float bcol = bias ? load_in(bias, col, fdt) : 0.0f;
#pragma unroll
    for (int m = 0; m < 8; ++m) {
#pragma unroll
      for (int u = 0; u < 4; ++u) {
        const int row = crow0 + m * 16 + quad * 4 + u;
        const size_t idx = (size_t)row * NC + col;
        float v = acc[m][n][u] + bcol;
        if (EPI == 0) {
          outb[idx] = f2bf(v);
        } else if (EPI == 1) {
          outf[idx] = v;
        } else if (EPI == 2) {
          const float pp = bf2f(res_hi[idx]) + bf2f(res_lo[idx]) + v;
          const u16 hi = f2bf(pp);
          outb[idx]  = hi;
          outb2[idx] = f2bf(pp - bf2f(hi));
        } else {  // EPI 4
          const u16 hi = f2bf(v);
          outb[idx]  = hi;
          outb2[idx] = f2bf(v - bf2f(hi));
        }
      }
    }
  }
}

// ---------------------------------------------------------------------------
// LayerNorm over D=1024 on raw input (dtype via flag); writes hi/lo bf16 pair.
// ---------------------------------------------------------------------------
__global__ __launch_bounds__(256) void ln_row(
    const void* __restrict__ x, const void* __restrict__ g, const void* __restrict__ b,
    const int* __restrict__ dflag, u16* __restrict__ oh, u16* __restrict__ ol)
{
  const int f = *dflag;
  const int row = blockIdx.x, tid = threadIdx.x;
  const int col = tid * 4;
  const size_t base = (size_t)row * 1024 + col;
  float v0, v1, v2, v3;
  if (f) {
    const float4 xv = *(const float4*)((const float*)x + base);
    v0 = xv.x; v1 = xv.y; v2 = xv.z; v3 = xv.w;
  } else {
    const ushort4 xv = *(const ushort4*)((const u16*)x + base);
    v0 = bf2f(xv.x); v1 = bf2f(xv.y); v2 = bf2f(xv.z); v3 = bf2f(xv.w);
  }
  float s  = v0 + v1 + v2 + v3;
  float sq = v0 * v0 + v1 * v1 + v2 * v2 + v3 * v3;
#pragma unroll
  for (int o = 32; o > 0; o >>= 1) { s += __shfl_xor(s, o); sq += __shfl_xor(sq, o); }
  __shared__ float red[8];
  if ((tid & 63) == 0) { red[tid >> 6] = s; red[4 + (tid >> 6)] = sq; }
  __syncthreads();
  s  = red[0] + red[1] + red[2] + red[3];
  sq = red[4] + red[5] + red[6] + red[7];
  const float mean = s * (1.0f / 1024.0f);
  const float var  = sq * (1.0f / 1024.0f) - mean * mean;
  const float rs   = rsqrtf(var + 1e-5f);
  float y[4];
  y[0] = (v0 - mean) * rs * load_in(g, col + 0, f) + load_in(b, col + 0, f);
  y[1] = (v1 - mean) * rs * load_in(g, col + 1, f) + load_in(b, col + 1, f);
  y[2] = (v2 - mean) * rs * load_in(g, col + 2, f) + load_in(b, col + 2, f);
  y[3] = (v3 - mean) * rs * load_in(g, col + 3, f) + load_in(b, col + 3, f);
  ushort4 hv, lv;
  hv.x = f2bf(y[0]); lv.x = f2bf(y[0] - bf2f(hv.x));
  hv.y = f2bf(y[1]); lv.y = f2bf(y[1] - bf2f(hv.y));
  hv.z = f2bf(y[2]); lv.z = f2bf(y[2] - bf2f(hv.z));
  hv.w = f2bf(y[3]); lv.w = f2bf(y[3] - bf2f(hv.w));
  *(ushort4*)(oh + base) = hv;
  *(ushort4*)(ol + base) = lv;
}

// ---------------------------------------------------------------------------
// LN + exact GELU on internal bf16 input; g/b raw dtype.
// MODE 0: write gelu bf16 (ob). MODE 1: p = res_hi+res_lo + gelu, hi/lo out.
// ---------------------------------------------------------------------------
template<int MODE>
__global__ __launch_bounds__(256) void ln_gelu(
    const u16* __restrict__ x, const void* __restrict__ g, const void* __restrict__ b,
    const int* __restrict__ dflag,
    const u16* res_hi, const u16* res_lo,
    u16* ob, u16* oh, u16* ol)
{
  const int f = *dflag;
  const int row = blockIdx.x, tid = threadIdx.x;
  const int col = tid * 4;
  const size_t base = (size_t)row * 1024 + col;
  const ushort4 xv = *(const ushort4*)(x + base);
  const float v0 = bf2f(xv.x), v1 = bf2f(xv.y), v2 = bf2f(xv.z), v3 = bf2f(xv.w);
  float s  = v0 + v1 + v2 + v3;
  float sq = v0 * v0 + v1 * v1 + v2 * v2 + v3 * v3;
#pragma unroll
  for (int o = 32; o > 0; o >>= 1) { s += __shfl_xor(s, o); sq += __shfl_xor(sq, o); }
  __shared__ float red[8];
  if ((tid & 63) == 0) { red[tid >> 6] = s; red[4 + (tid >> 6)] = sq; }
  __syncthreads();
  s  = red[0] + red[1] + red[2] + red[3];
  sq = red[4] + red[5] + red[6] + red[7];
  const float mean = s * (1.0f / 1024.0f);
  const float var  = sq * (1.0f / 1024.0f) - mean * mean;
  const float rs   = rsqrtf(var + 1e-5f);
  float z[4], h[4];
  z[0] = (v0 - mean) * rs * load_in(g, col + 0, f) + load_in(b, col + 0, f);
  z[1] = (v1 - mean) * rs * load_in(g, col + 1, f) + load_in(b, col + 1, f);
  z[2] = (v2 - mean) * rs * load_in(g, col + 2, f) + load_in(b, col + 2, f);
  z[3] = (v3 - mean) * rs * load_in(g, col + 3, f) + load_in(b, col + 3, f);
#pragma unroll
  for (int i = 0; i < 4; ++i)
    h[i] = 0.5f * z[i] * (1.0f + erff(z[i] * 0.70710678118654752f));
  if (MODE == 0) {
    *(ushort4*)(ob + base) = make_ushort4(f2bf(h[0]), f2bf(h[1]), f2bf(h[2]), f2bf(h[3]));
  } else {
    const ushort4 rh = *(const ushort4*)(res_hi + base);
    const ushort4 rl = *(const ushort4*)(res_lo + base);
    float p[4];
    p[0] = bf2f(rh.x) + bf2f(rl.x) + h[0];
    p[1] = bf2f(rh.y) + bf2f(rl.y) + h[1];
    p[2] = bf2f(rh.z) + bf2f(rl.z) + h[2];
    p[3] = bf2f(rh.w) + bf2f(rl.w) + h[3];
    ushort4 hv, lv;
    hv.x = f2bf(p[0]); lv.x = f2bf(p[0] - bf2f(hv.x));
    hv.y = f2bf(p[1]); lv.y = f2bf(p[1] - bf2f(hv.y));
    hv.z = f2bf(p[2]); lv.z = f2bf(p[2] - bf2f(hv.z));
    hv.w = f2bf(p[3]); lv.w = f2bf(p[3] - bf2f(hv.w));
    *(ushort4*)(oh + base) = hv;
    *(ushort4*)(ol + base) = lv;
  }
}

// ---------------------------------------------------------------------------
// Softmax over M=256; one wave per row, 4 rows per block. f32 in, bf16 out.
// ---------------------------------------------------------------------------
__global__ __launch_bounds__(256) void softmax256(const float* __restrict__ S, u16* __restrict__ A)
{
  const int tid = threadIdx.x, lane = tid & 63, wave = tid >> 6;
  const size_t row = (size_t)blockIdx.x * 4 + wave;
  const float4 v = *(const float4*)(S + row * 256 + lane * 4);
  float m = fmaxf(fmaxf(v.x, v.y), fmaxf(v.z, v.w));
#pragma unroll
  for (int o = 32; o > 0; o >>= 1) m = fmaxf(m, __shfl_xor(m, o));
  const float e0 = expf(v.x - m), e1 = expf(v.y - m), e2 = expf(v.z - m), e3 = expf(v.w - m);
  float s = e0 + e1 + e2 + e3;
#pragma unroll
  for (int o = 32; o > 0; o >>= 1) s += __shfl_xor(s, o);
  const float r = 1.0f / s;
  *(ushort4*)(A + row * 256 + lane * 4) =
      make_ushort4(f2bf(e0 * r), f2bf(e1 * r), f2bf(e2 * r), f2bf(e3 * r));
}

// ---------------------------------------------------------------------------
// Weight transpose->bf16 hi/lo from raw dtype: Wt[n][k] = W[k][n], 5 matrices.
// ---------------------------------------------------------------------------
__global__ __launch_bounds__(256) void wtrans5(
    const void* w0, const void* w1, const void* w2, const void* w3, const void* w4,
    u16* h0, u16* h1, u16* h2, u16* h3, u16* h4,
    u16* l0, u16* l1, u16* l2, u16* l3, u16* l4,
    const int* __restrict__ dflag)
{
  const int f = *dflag;
  const void* W; u16* H; u16* L;
  switch (blockIdx.z) {
    case 0: W = w0; H = h0; L = l0; break;
    case 1: W = w1; H = h1; L = l1; break;
    case 2: W = w2; H = h2; L = l2; break;
    case 3: W = w3; H = h3; L = l3; break;
    default: W = w4; H = h4; L = l4; break;
  }
  __shared__ u16 th[32][33];
  __shared__ u16 tl[32][33];
  const int tx = threadIdx.x & 31, ty = threadIdx.x >> 5;
  const int bx = blockIdx.x, by = blockIdx.y;
#pragma unroll
  for (int i = 0; i < 4; ++i) {
    const int r = ty + i * 8;
    const float v = load_in(W, ((size_t)by * 32 + r) * 1024 + bx * 32 + tx, f);
    const u16 hi = f2bf(v);
    th[r][tx] = hi;
    tl[r][tx] = f2bf(v - bf2f(hi));
  }
  __syncthreads();
#pragma unroll
  for (int i = 0; i < 4; ++i) {
    const int r = ty + i * 8;
    const size_t o = ((size_t)bx * 32 + r) * 1024 + by * 32 + tx;
    H[o] = th[tx][r];
    L[o] = tl[tx][r];
  }
}

__global__ __launch_bounds__(256) void zerof(float* p, int n)
{
  const int i = blockIdx.x * 256 + threadIdx.x;
  if (i < n) p[i] = 0.0f;
}

// ---------------------------------------------------------------------------
// BCIM phase 1: 9-offset Gram band on p2 = hi+lo. grid = (B, 8 d-splits).
// ---------------------------------------------------------------------------
__global__ __launch_bounds__(256) void bcim_dots(
    const u16* __restrict__ p2h, const u16* __restrict__ p2l, float* __restrict__ G)
{
  const int b = blockIdx.x, ds = blockIdx.y;
  __shared__ float T[512][17];
  float acc[9] = {0, 0, 0, 0, 0, 0, 0, 0, 0};
  const int tid = threadIdx.x;
  const int px = tid & 15, py = tid >> 4;
  for (int ch = 0; ch < 8; ++ch) {
    const int d0 = ds * 128 + ch * 16;
#pragma unroll
    for (int i = 0; i < 8; ++i) {
      const int j = i * 256 + tid;
      const int r = j >> 2, q4 = j & 3;
      const size_t base = ((size_t)b * 512 + r) * 1024 + d0 + q4 * 4;
      const ushort4 hv = *(const ushort4*)(p2h + base);
      const ushort4 lv = *(const ushort4*)(p2l + base);
      T[r][q4 * 4 + 0] = bf2f(hv.x) + bf2f(lv.x);
      T[r][q4 * 4 + 1] = bf2f(hv.y) + bf2f(lv.y);
      T[r][q4 * 4 + 2] = bf2f(hv.z) + bf2f(lv.z);
      T[r][q4 * 4 + 3] = bf2f(hv.w) + bf2f(lv.w);
    }
    __syncthreads();
    float a0[16], a1[16];
#pragma unroll
    for (int dc = 0; dc < 16; ++dc) { a0[dc] = T[tid][dc]; a1[dc] = T[tid + 256][dc]; }
#pragma unroll
    for (int o = 0; o < 9; ++o) {
      const int dy = o / 3 - 1, dx = o % 3 - 1;
      const int qx = px + dx, qy = py + dy;
      if (qx >= 0 && qx < 16 && qy >= 0 && qy < 16) {
        const int qp = qy * 16 + qx;
        float sum = 0.0f;
#pragma unroll
        for (int dc = 0; dc < 16; ++dc)
          sum += a0[dc] * T[qp][dc] + a1[dc] * T[qp + 256][dc];
        acc[o] += sum;
      }
    }
    __syncthreads();
  }
#pragma unroll
  for (int o = 0; o < 9; ++o)
    atomicAdd(&G[((size_t)b * 9 + o) * 256 + tid], acc[o]);
}

// BCIM phase 2: sim[b][pix]
__global__ __launch_bounds__(256) void bcim_sim_k(const float* __restrict__ G, float* __restrict__ sim)
{
  const int b = blockIdx.x, tid = threadIdx.x;
  __shared__ float nrm[256];
  const float nv = sqrtf(G[((size_t)b * 9 + 4) * 256 + tid]);
  nrm[tid] = nv;
  __syncthreads();
  const int px = tid & 15, py = tid >> 4;
  float s = 0.0f;
#pragma unroll
  for (int o = 0; o < 9; ++o) {
    const int dy = o / 3 - 1, dx = o % 3 - 1;
    const int qx = px + dx, qy = py + dy;
    if (qx >= 0 && qx < 16 && qy >= 0 && qy < 16)
      s += G[((size_t)b * 9 + o) * 256 + tid] / (nv * nrm[qy * 16 + qx]);
  }
  sim[b * 256 + tid] = s * (1.0f / 9.0f);
}

// BCIM phase 3: out[b,n,d] = (p2h+p2l)[b,n,d] * sim[b][n&255]  (f32 out)
__global__ __launch_bounds__(256) void bcim_scale(
    const u16* __restrict__ p2h, const u16* __restrict__ p2l,
    const float* __restrict__ sim, float* __restrict__ out)
{
  const size_t i4 = (size_t)blockIdx.x * 256 + threadIdx.x;
  const size_t base = i4 * 4;
  const ushort4 hv = *(const ushort4*)(p2h + base);
  const ushort4 lv = *(const ushort4*)(p2l + base);
  const size_t n = base >> 10;
  const size_t b = n >> 9;
  const int pix = (int)(n & 255);
  const float s = sim[b * 256 + pix];
  *(float4*)(out + base) = make_float4(
      (bf2f(hv.x) + bf2f(lv.x)) * s, (bf2f(hv.y) + bf2f(lv.y)) * s,
      (bf2f(hv.z) + bf2f(lv.z)) * s, (bf2f(hv.w) + bf2f(lv.w)) * s);
}

// ---------------------------------------------------------------------------
extern "C" void kernel_launch(void* const* d_in, const int* in_sizes, int n_in,
                              void* d_out, int out_size, void* d_ws, size_t ws_size,
                              hipStream_t stream)
{
  (void)in_sizes; (void)n_in; (void)out_size; (void)ws_size;
  const void* p_vector      = d_in[0];
  const void* object_vector = d_in[1];
  const void* ln_p_g = d_in[2];
  const void* ln_p_b = d_in[3];
  const void* ln_o_g = d_in[4];
  const void* ln_o_b = d_in[5];
  const void* Wq = d_in[6];  const void* bq = d_in[7];
  const void* Wk = d_in[8];  const void* bk = d_in[9];
  const void* Wv = d_in[10]; const void* bv = d_in[11];
  const void* W1 = d_in[12]; const void* b1 = d_in[13];
  const void* ln1_g = d_in[14]; const void* ln1_b = d_in[15];
  const void* W2 = d_in[16]; const void* b2 = d_in[17];
  const void* ln2_g = d_in[18]; const void* ln2_b = d_in[19];
  float* out = (float*)d_out;

  char* ws = (char*)d_ws;
  size_t off = 0;
  auto alloc = [&](size_t bytes) -> void* {
    void* p = ws + off;
    off += (bytes + 255) & ~(size_t)255;
    return p;
  };
  int* dflag = (int*)alloc(256);
  u16* WqH = (u16*)alloc((size_t)D_DIM * D_DIM * 2);
  u16* WkH = (u16*)alloc((size_t)D_DIM * D_DIM * 2);
  u16* WvH = (u16*)alloc((size_t)D_DIM * D_DIM * 2);
  u16* W1H = (u16*)alloc((size_t)D_DIM * D_DIM * 2);
  u16* W2H = (u16*)alloc((size_t)D_DIM * D_DIM * 2);
  u16* WqL = (u16*)alloc((size_t)D_DIM * D_DIM * 2);
  u16* WkL = (u16*)alloc((size_t)D_DIM * D_DIM * 2);
  u16* WvL = (u16*)alloc((size_t)D_DIM * D_DIM * 2);
  u16* W1L = (u16*)alloc((size_t)D_DIM * D_DIM * 2);
  u16* W2L = (u16*)alloc((size_t)D_DIM * D_DIM * 2);
  u16* PH = (u16*)alloc((size_t)BN * D_DIM * 2);   // pn_hi -> p1_hi -> p2_hi
  u16* PL = (u16*)alloc((size_t)BN * D_DIM * 2);   // pn_lo -> p1_lo -> p2_lo
  u16* QH = (u16*)alloc((size_t)BN * D_DIM * 2);   // q_hi -> y1 -> y2
  u16* QL = (u16*)alloc((size_t)BN * D_DIM * 2);   // q_lo -> h1
  float* S_f = (float*)alloc((size_t)BN * M_DIM * 4);
  u16* A_b   = (u16*)alloc((size_t)BN * M_DIM * 2);
  u16* onH = (u16*)alloc((size_t)M_DIM * D_DIM * 2);
  u16* onL = (u16*)alloc((size_t)M_DIM * D_DIM * 2);
  u16* kH  = (u16*)alloc((size_t)M_DIM * D_DIM * 2);
  u16* kL  = (u16*)alloc((size_t)M_DIM * D_DIM * 2);
  u16* vT  = (u16*)alloc((size_t)D_DIM * M_DIM * 2);
  float* G   = (float*)alloc((size_t)B_IMG * 9 * 256 * 4);
  float* sim = (float*)alloc((size_t)B_IMG * 256 * 4);

  // 0. dtype detect, weight transposes (hi/lo), zero G
  detect_dtype<<<1, 64, 0, stream>>>((const u16*)p_vector, dflag);
  wtrans5<<<dim3(32, 32, 5), 256, 0, stream>>>(Wq, Wk, Wv, W1, W2,
      WqH, WkH, WvH, W1H, W2H, WqL, WkL, WvL, W1L, W2L, dflag);
  zerof<<<(B_IMG * 9 * 256 + 255) / 256, 256, 0, stream>>>(G, B_IMG * 9 * 256);

  // 1. LayerNorms -> hi/lo pairs
  ln_row<<<BN, 256, 0, stream>>>(p_vector, ln_p_g, ln_p_b, dflag, PH, PL);
  ln_row<<<M_DIM, 256, 0, stream>>>(object_vector, ln_o_g, ln_o_b, dflag, onH, onL);

  // 2. k (hi/lo), v^T on old 128^2 kernel (R=256); q on new 256^2 pipeline
  gemm_bt<4><<<dim3(2, 8), 256, 0, stream>>>(onH, onL, onH, WkH, WkH, WkL,
      bk, dflag, 2, 1, nullptr, nullptr, nullptr, kH, kL, M_DIM, D_DIM, D_DIM);
  gemm_bt<3><<<dim3(2, 8), 256, 0, stream>>>(onH, onL, onH, WvH, WvH, WvL,
      bv, dflag, 2, 1, nullptr, nullptr, nullptr, vT, nullptr, M_DIM, D_DIM, D_DIM);
  gemm256<4><<<dim3(128, 4), 512, 131072, stream>>>(PH, PL, PH, WqH, WqH, WqL,
      bq, dflag, 2, 1, nullptr, nullptr, nullptr, QH, QL, BN, D_DIM, D_DIM);

  // 3. S = (q_hi+q_lo)(k_hi+k_lo)^T (3 split passes); softmax -> A bf16
  gemm256<1><<<dim3(128, 1), 512, 131072, stream>>>(QH, QL, QH, kH, kH, kL,
      nullptr, dflag, 3, 0, nullptr, nullptr, S_f, nullptr, nullptr, BN, D_DIM, M_DIM);
  softmax256<<<BN / 4, 256, 0, stream>>>(S_f, A_b);

  // 4. p1 = pn + A v  (in-place hi/lo over PH/PL)
  gemm256<2><<<dim3(128, 4), 512, 131072, stream>>>(A_b, nullptr, nullptr, vT, nullptr, nullptr,
      nullptr, dflag, 1, 0, PH, PL, nullptr, PH, PL, BN, M_DIM, D_DIM);

  // 5. y1 = p1_hi W1 + b1 -> QH ; h1 = gelu(LN(y1)) -> QL
  gemm256<0><<<dim3(128, 4), 512, 131072, stream>>>(PH, nullptr, nullptr, W1H, nullptr, nullptr,
      b1, dflag, 1, 0, nullptr, nullptr, nullptr, QH, nullptr, BN, D_DIM, D_DIM);
  ln_gelu<0><<<BN, 256, 0, stream>>>(QH, ln1_g, ln1_b, dflag, nullptr, nullptr, QL, nullptr, nullptr);

  // 6. y2 = h1 W2 + b2 -> QH ; p2 = p1 + gelu(LN(y2)) (in-place hi/lo)
  gemm256<0><<<dim3(128, 4), 512, 131072, stream>>>(QL, nullptr, nullptr, W2H, nullptr, nullptr,
      b2, dflag, 1, 0, nullptr, nullptr, nullptr, QH, nullptr, BN, D_DIM, D_DIM);
  ln_gelu<1><<<BN, 256, 0, stream>>>(QH, ln2_g, ln2_b, dflag, PH, PL, nullptr, PH, PL);

  // 7. BCIM
  bcim_dots<<<dim3(B_IMG, 8), 256, 0, stream>>>(PH, PL, G);
  bcim_sim_k<<<B_IMG, 256, 0, stream>>>(G, sim);
  bcim_scale<<<(BN * D_DIM / 4) / 256, 256, 0, stream>>>(PH, PL, sim, out);
}

// Round 2
// 1565.392 us; speedup vs baseline: 1.0002x; 1.0002x over previous
//
#include <hip/hip_runtime.h>
#include <math.h>

#define D_DIM 1024
#define M_DIM 256
#define B_IMG 64
#define N_TOK 512
#define BN    32768

typedef unsigned short u16;
typedef __attribute__((ext_vector_type(8))) __bf16 bf16x8;
typedef __attribute__((ext_vector_type(4))) float  f32x4;

__device__ __forceinline__ u16 f2bf(float f) {
  union { float f; unsigned u; } c; c.f = f;
  unsigned u = c.u;
  return (u16)((u + 0x7FFFu + ((u >> 16) & 1u)) >> 16);
}
__device__ __forceinline__ float bf2f(u16 h) {
  union { unsigned u; float f; } c; c.u = ((unsigned)h) << 16;
  return c.f;
}

// ---------------------------------------------------------------------------
// Input-dtype detector. flag: 0 = inputs are bf16, 1 = inputs are f32.
// ---------------------------------------------------------------------------
__global__ __launch_bounds__(64) void detect_dtype(const u16* __restrict__ p, int* __restrict__ dflag)
{
  const int lane = threadIdx.x;
  const float a = fabsf(bf2f(p[lane * 2]));
  const bool sane = (a >= 1e-20f && a <= 1e3f);
  const unsigned long long m = __ballot(sane);
  if (lane == 0) *dflag = (m == ~0ull) ? 0 : 1;
}

__device__ __forceinline__ float load_in(const void* p, size_t i, int f) {
  return f ? ((const float*)p)[i] : bf2f(((const u16*)p)[i]);
}

// ---------------------------------------------------------------------------
// 128x128 multi-pass GEMM — used for small/narrow shapes (k, v, S).
// EPI: 0 bf16, 1 f32, 2 res+hi/lo, 3 bf16 transposed, 4 hi/lo split.
// ---------------------------------------------------------------------------
template<int EPI>
__global__ __launch_bounds__(256) void gemm_bt(
    const u16* __restrict__ X0, const u16* __restrict__ X1, const u16* __restrict__ X2,
    const u16* __restrict__ Bt0, const u16* __restrict__ Bt1, const u16* __restrict__ Bt2,
    const void* __restrict__ bias, const int* __restrict__ dflag,
    int np_base, int np_extra,
    const u16* res_hi, const u16* res_lo,
    float* outf, u16* outb, u16* outb2,
    int R, int K, int NC)
{
  __shared__ u16 lA[128 * 64];
  __shared__ u16 lB[128 * 64];
  const int tid  = threadIdx.x;
  const int wave = tid >> 6, lane = tid & 63;
  const int quad = lane >> 4, l15 = lane & 15;
  const int wr = wave & 1, wc = wave >> 1;
  const int rblk = blockIdx.x, cblk = blockIdx.y;

  const int np = np_base + (np_extra ? np_extra * (*dflag) : 0);

  const int srow = lane >> 3;
  const int scol = ((lane & 7) ^ (srow & 7)) * 8;

  const u16* Xs[3] = {X0, X1, X2};
  const u16* Bs[3] = {Bt0, Bt1, Bt2};

  f32x4 acc[4][4] = {};

  for (int p = 0; p < np; ++p) {
    const u16* gA = Xs[p] + (size_t)(rblk * 128 + srow) * K + scol;
    const u16* gB = Bs[p] + (size_t)(cblk * 128 + srow) * K + scol;
    for (int k0 = 0; k0 < K; k0 += 64) {
#pragma unroll
      for (int i = 0; i < 4; ++i) {
        const int j = i * 4 + wave;
        __builtin_amdgcn_global_load_lds(
            (const __attribute__((address_space(1))) void*)(gA + (size_t)j * 8 * K + k0),
            (__attribute__((address_space(3))) void*)(lA + j * 512), 16, 0, 0);
        __builtin_amdgcn_global_load_lds(
            (const __attribute__((address_space(1))) void*)(gB + (size_t)j * 8 * K + k0),
            (__attribute__((address_space(3))) void*)(lB + j * 512), 16, 0, 0);
      }
      __syncthreads();
#pragma unroll
      for (int s = 0; s < 2; ++s) {
        bf16x8 af[4], bfr[4];
#pragma unroll
        for (int r = 0; r < 4; ++r) {
          const int row  = wr * 64 + r * 16 + l15;
          const int slot = (s * 4 + quad) ^ (row & 7);
          af[r] = *(const bf16x8*)(lA + row * 64 + slot * 8);
        }
#pragma unroll
        for (int c = 0; c < 4; ++c) {
          const int row  = wc * 64 + c * 16 + l15;
          const int slot = (s * 4 + quad) ^ (row & 7);
          bfr[c] = *(const bf16x8*)(lB + row * 64 + slot * 8);
        }
#pragma unroll
        for (int r = 0; r < 4; ++r)
#pragma unroll
          for (int c = 0; c < 4; ++c)
            acc[r][c] = __builtin_amdgcn_mfma_f32_16x16x32_bf16(af[r], bfr[c], acc[r][c], 0, 0, 0);
      }
      __syncthreads();
    }
  }

  const int fdt = bias ? *dflag : 0;
  const int crow0 = rblk * 128 + wr * 64;
  const int ccol0 = cblk * 128 + wc * 64;
#pragma unroll
  for (int c = 0; c < 4; ++c) {
    const int col = ccol0 + c * 16 + l15;
    const float bcol = bias ? load_in(bias, col, fdt) : 0.0f;
#pragma unroll
    for (int r = 0; r < 4; ++r) {
#pragma unroll
      for (int t = 0; t < 4; ++t) {
        const int row = crow0 + r * 16 + quad * 4 + t;
        const size_t idx = (size_t)row * NC + col;
        float v = acc[r][c][t] + bcol;
        if (EPI == 0) {
          outb[idx] = f2bf(v);
        } else if (EPI == 1) {
          outf[idx] = v;
        } else if (EPI == 2) {
          const float p = bf2f(res_hi[idx]) + bf2f(res_lo[idx]) + v;
          const u16 hi = f2bf(p);
          outb[idx]  = hi;
          outb2[idx] = f2bf(p - bf2f(hi));
        } else if (EPI == 3) {
          outb[(size_t)col * R + row] = f2bf(v);
        } else {  // EPI 4: hi/lo split
          const u16 hi = f2bf(v);
          outb[idx]  = hi;
          outb2[idx] = f2bf(v - bf2f(hi));
        }
      }
    }
  }
}

// ---------------------------------------------------------------------------
// 256x256-tile 8-wave GEMM, fine-phase pipeline (m201-style):
// BK=32 K-tiles in a 4-slot LDS ring (4 x 32 KiB = 128 KiB). Per tile, two
// phases: {ds_read frags, stage tile t+2, barrier, lgkmcnt(0), 16 MFMA,
// barrier}. One counted s_waitcnt vmcnt(4) per tile (never 0 in the loop):
// per-wave FIFO at tile t ph1 = [t+1's 4 loads][t+2's 4 loads]; vmcnt(4)
// drains tile t+1 (issued 3 phases earlier - pre-satisfied). 4-slot ring =>
// the slot staged at tile t was last read at tile t-2 (4 barriers earlier).
// Tail stages clamp the source tile but keep slot/wait/barrier structure
// uniform; clamped loads land in a never-again-read slot.
// LDS swizzle: phys_slot = quad ^ ((row>>1)&3) -> 2-way (free) on
// ds_read_b128 at 64B row stride; inverse applied on per-lane global src.
// EPI: 0 bf16, 1 f32, 2 res+hi/lo, 4 hi/lo split.
// Requires: R%256==0, NC%256==0, K%32==0 pow2 tiles, NT>=2.
// ---------------------------------------------------------------------------
template<int EPI>
__global__ __launch_bounds__(512, 2) void gemm256(
    const u16* __restrict__ X0, const u16* __restrict__ X1, const u16* __restrict__ X2,
    const u16* __restrict__ Bt0, const u16* __restrict__ Bt1, const u16* __restrict__ Bt2,
    const void* __restrict__ bias, const int* __restrict__ dflag,
    int np_base, int np_extra,
    const u16* res_hi, const u16* res_lo,
    float* outf, u16* outb, u16* outb2,
    int R, int K, int NC)
{
  extern __shared__ u16 lds2[];   // 4 slots x (A 256x32 | B 256x32) u16
  const int tid  = threadIdx.x;
  const int wave = tid >> 6, lane = tid & 63;
  const int quad = lane >> 4, l15 = lane & 15;
  const int wm = wave >> 2, wn = wave & 3;     // 2x4 wave grid
  const int rblk = blockIdx.x, cblk = blockIdx.y;

  const int np = np_base + (np_extra ? np_extra * (*dflag) : 0);
  const int ktiles = K >> 5;                    // BK=32 tiles per pass (pow2)
  const int ktl = 31 - __builtin_clz(ktiles);
  const int NT = np << ktl;

  const u16* Xs[3] = {X0, X1, X2};
  const u16* Bs[3] = {Bt0, Bt1, Bt2};

  // staging: one gload covers 16 rows x 4 slots (lane -> row lane>>2,
  // phys slot lane&3). Source col-group pre-swizzled so LDS phys slot s of
  // row r holds logical group s ^ ((r>>1)&3)  (self-inverse).
  const int srow  = lane >> 2;
  const int sslot = lane & 3;

  f32x4 acc[8][4] = {};

  auto stage_tile = [&](int t) {
    const int tc = t < NT ? t : NT - 1;        // clamp (uniform tail)
    const int p  = tc >> ktl;
    const int k0 = (tc & (ktiles - 1)) << 5;
    u16* dst = lds2 + (t & 3) * 16384;         // 32 KiB slot (in u16)
#pragma unroll
    for (int i = 0; i < 2; ++i) {
      const int rbase = wave * 32 + i * 16;
      const int r  = rbase + srow;
      const int cg = (sslot ^ ((r >> 1) & 3)) * 8;
      __builtin_amdgcn_global_load_lds(
          (const __attribute__((address_space(1))) void*)(Xs[p] + (size_t)(rblk * 256 + r) * K + k0 + cg),
          (__attribute__((address_space(3))) void*)(dst + rbase * 32), 16, 0, 0);
    }
#pragma unroll
    for (int i = 0; i < 2; ++i) {
      const int rbase = wave * 32 + i * 16;
      const int r  = rbase + srow;
      const int cg = (sslot ^ ((r >> 1) & 3)) * 8;
      __builtin_amdgcn_global_load_lds(
          (const __attribute__((address_space(1))) void*)(Bs[p] + (size_t)(cblk * 256 + r) * K + k0 + cg),
          (__attribute__((address_space(3))) void*)(dst + 8192 + rbase * 32), 16, 0, 0);
    }
  };

  // prologue: tiles 0,1 staged (8 loads); confirm tile 0, keep tile 1 in flight
  stage_tile(0);
  stage_tile(1);
  asm volatile("s_waitcnt vmcnt(4)" ::: "memory");
  __builtin_amdgcn_s_barrier();

  for (int t = 0; t < NT; ++t) {
    const u16* bufA = lds2 + (t & 3) * 16384;
    const u16* bufB = bufA + 8192;
    bf16x8 bfr[4], af[4];
    // ---- phase 0: B frags (4) + A frags m0-3 (4); stage tile t+2 ----
#pragma unroll
    for (int n = 0; n < 4; ++n) {
      const int row = wn * 64 + n * 16 + l15;
      const int ps  = quad ^ ((row >> 1) & 3);
      bfr[n] = *(const bf16x8*)(bufB + row * 32 + ps * 8);
    }
#pragma unroll
    for (int m = 0; m < 4; ++m) {
      const int row = wm * 128 + m * 16 + l15;
      const int ps  = quad ^ ((row >> 1) & 3);
      af[m] = *(const bf16x8*)(bufA + row * 32 + ps * 8);
    }
    stage_tile(t + 2);
    __builtin_amdgcn_s_barrier();
    asm volatile("s_waitcnt lgkmcnt(0)" ::: "memory");
    __builtin_amdgcn_s_setprio(1);
#pragma unroll
    for (int m = 0; m < 4; ++m)
#pragma unroll
      for (int n = 0; n < 4; ++n)
        acc[m][n] = __builtin_amdgcn_mfma_f32_16x16x32_bf16(af[m], bfr[n], acc[m][n], 0, 0, 0);
    __builtin_amdgcn_s_setprio(0);
    __builtin_amdgcn_s_barrier();
    // ---- phase 1: A frags m4-7 (4); counted vmcnt for tile t+1 ----
#pragma unroll
    for (int m = 0; m < 4; ++m) {
      const int row = wm * 128 + 64 + m * 16 + l15;
      const int ps  = quad ^ ((row >> 1) & 3);
      af[m] = *(const bf16x8*)(bufA + row * 32 + ps * 8);
    }
    asm volatile("s_waitcnt vmcnt(4)" ::: "memory");
    __builtin_amdgcn_s_barrier();
    asm volatile("s_waitcnt lgkmcnt(0)" ::: "memory");
    __builtin_amdgcn_s_setprio(1);
#pragma unroll
    for (int m = 0; m < 4; ++m)
#pragma unroll
      for (int n = 0; n < 4; ++n)
        acc[4 + m][n] = __builtin_amdgcn_mfma_f32_16x16x32_bf16(af[m], bfr[n], acc[4 + m][n], 0, 0, 0);
    __builtin_amdgcn_s_setprio(0);
    __builtin_amdgcn_s_barrier();
  }

  const int fdt = bias ? *dflag : 0;
  const int crow0 = rblk * 256 + wm * 128;
  const int ccol0 = cblk * 256 + wn * 64;
#pragma unroll
  for (int n = 0; n < 4; ++n) {
    const int col = ccol0 + n * 16 + l15;
    const float bcol = bias ? load_in(bias, col, fdt) : 0.0f;
#pragma unroll
    for (int m = 0; m < 8; ++m) {
#pragma unroll
      for (int u = 0; u < 4; ++u) {
        const int row = crow0 + m * 16 + quad * 4 + u;
        const size_t idx = (size_t)row * NC + col;
        float v = acc[m][n][u] + bcol;
        if (EPI == 0) {
          outb[idx] = f2bf(v);
        } else if (EPI == 1) {
          outf[idx] = v;
        } else if (EPI == 2) {
          const float pp = bf2f(res_hi[idx]) + bf2f(res_lo[idx]) + v;
          const u16 hi = f2bf(pp);
          outb[idx]  = hi;
          outb2[idx] = f2bf(pp - bf2f(hi));
        } else {  // EPI 4
          const u16 hi = f2bf(v);
          outb[idx]  = hi;
          outb2[idx] = f2bf(v - bf2f(hi));
        }
      }
    }
  }
}

// ---------------------------------------------------------------------------
// LayerNorm over D=1024 on raw input (dtype via flag); writes hi/lo bf16 pair.
// ---------------------------------------------------------------------------
__global__ __launch_bounds__(256) void ln_row(
    const void* __restrict__ x, const void* __restrict__ g, const void* __restrict__ b,
    const int* __restrict__ dflag, u16* __restrict__ oh, u16* __restrict__ ol)
{
  const int f = *dflag;
  const int row = blockIdx.x, tid = threadIdx.x;
  const int col = tid * 4;
  const size_t base = (size_t)row * 1024 + col;
  float v0, v1, v2, v3;
  if (f) {
    const float4 xv = *(const float4*)((const float*)x + base);
    v0 = xv.x; v1 = xv.y; v2 = xv.z; v3 = xv.w;
  } else {
    const ushort4 xv = *(const ushort4*)((const u16*)x + base);
    v0 = bf2f(xv.x); v1 = bf2f(xv.y); v2 = bf2f(xv.z); v3 = bf2f(xv.w);
  }
  float s  = v0 + v1 + v2 + v3;
  float sq = v0 * v0 + v1 * v1 + v2 * v2 + v3 * v3;
#pragma unroll
  for (int o = 32; o > 0; o >>= 1) { s += __shfl_xor(s, o); sq += __shfl_xor(sq, o); }
  __shared__ float red[8];
  if ((tid & 63) == 0) { red[tid >> 6] = s; red[4 + (tid >> 6)] = sq; }
  __syncthreads();
  s  = red[0] + red[1] + red[2] + red[3];
  sq = red[4] + red[5] + red[6] + red[7];
  const float mean = s * (1.0f / 1024.0f);
  const float var  = sq * (1.0f / 1024.0f) - mean * mean;
  const float rs   = rsqrtf(var + 1e-5f);
  float y[4];
  y[0] = (v0 - mean) * rs * load_in(g, col + 0, f) + load_in(b, col + 0, f);
  y[1] = (v1 - mean) * rs * load_in(g, col + 1, f) + load_in(b, col + 1, f);
  y[2] = (v2 - mean) * rs * load_in(g, col + 2, f) + load_in(b, col + 2, f);
  y[3] = (v3 - mean) * rs * load_in(g, col + 3, f) + load_in(b, col + 3, f);
  ushort4 hv, lv;
  hv.x = f2bf(y[0]); lv.x = f2bf(y[0] - bf2f(hv.x));
  hv.y = f2bf(y[1]); lv.y = f2bf(y[1] - bf2f(hv.y));
  hv.z = f2bf(y[2]); lv.z = f2bf(y[2] - bf2f(hv.z));
  hv.w = f2bf(y[3]); lv.w = f2bf(y[3] - bf2f(hv.w));
  *(ushort4*)(oh + base) = hv;
  *(ushort4*)(ol + base) = lv;
}

// ---------------------------------------------------------------------------
// LN + exact GELU on internal bf16 input; g/b raw dtype.
// MODE 0: write gelu bf16 (ob). MODE 1: p = res_hi+res_lo + gelu, hi/lo out.
// ---------------------------------------------------------------------------
template<int MODE>
__global__ __launch_bounds__(256) void ln_gelu(
    const u16* __restrict__ x, const void* __restrict__ g, const void* __restrict__ b,
    const int* __restrict__ dflag,
    const u16* res_hi, const u16* res_lo,
    u16* ob, u16* oh, u16* ol)
{
  const int f = *dflag;
  const int row = blockIdx.x, tid = threadIdx.x;
  const int col = tid * 4;
  const size_t base = (size_t)row * 1024 + col;
  const ushort4 xv = *(const ushort4*)(x + base);
  const float v0 = bf2f(xv.x), v1 = bf2f(xv.y), v2 = bf2f(xv.z), v3 = bf2f(xv.w);
  float s  = v0 + v1 + v2 + v3;
  float sq = v0 * v0 + v1 * v1 + v2 * v2 + v3 * v3;
#pragma unroll
  for (int o = 32; o > 0; o >>= 1) { s += __shfl_xor(s, o); sq += __shfl_xor(sq, o); }
  __shared__ float red[8];
  if ((tid & 63) == 0) { red[tid >> 6] = s; red[4 + (tid >> 6)] = sq; }
  __syncthreads();
  s  = red[0] + red[1] + red[2] + red[3];
  sq = red[4] + red[5] + red[6] + red[7];
  const float mean = s * (1.0f / 1024.0f);
  const float var  = sq * (1.0f / 1024.0f) - mean * mean;
  const float rs   = rsqrtf(var + 1e-5f);
  float z[4], h[4];
  z[0] = (v0 - mean) * rs * load_in(g, col + 0, f) + load_in(b, col + 0, f);
  z[1] = (v1 - mean) * rs * load_in(g, col + 1, f) + load_in(b, col + 1, f);
  z[2] = (v2 - mean) * rs * load_in(g, col + 2, f) + load_in(b, col + 2, f);
  z[3] = (v3 - mean) * rs * load_in(g, col + 3, f) + load_in(b, col + 3, f);
#pragma unroll
  for (int i = 0; i < 4; ++i)
    h[i] = 0.5f * z[i] * (1.0f + erff(z[i] * 0.70710678118654752f));
  if (MODE == 0) {
    *(ushort4*)(ob + base) = make_ushort4(f2bf(h[0]), f2bf(h[1]), f2bf(h[2]), f2bf(h[3]));
  } else {
    const ushort4 rh = *(const ushort4*)(res_hi + base);
    const ushort4 rl = *(const ushort4*)(res_lo + base);
    float p[4];
    p[0] = bf2f(rh.x) + bf2f(rl.x) + h[0];
    p[1] = bf2f(rh.y) + bf2f(rl.y) + h[1];
    p[2] = bf2f(rh.z) + bf2f(rl.z) + h[2];
    p[3] = bf2f(rh.w) + bf2f(rl.w) + h[3];
    ushort4 hv, lv;
    hv.x = f2bf(p[0]); lv.x = f2bf(p[0] - bf2f(hv.x));
    hv.y = f2bf(p[1]); lv.y = f2bf(p[1] - bf2f(hv.y));
    hv.z = f2bf(p[2]); lv.z = f2bf(p[2] - bf2f(hv.z));
    hv.w = f2bf(p[3]); lv.w = f2bf(p[3] - bf2f(hv.w));
    *(ushort4*)(oh + base) = hv;
    *(ushort4*)(ol + base) = lv;
  }
}

// ---------------------------------------------------------------------------
// Softmax over M=256; one wave per row, 4 rows per block. f32 in, bf16 out.
// ---------------------------------------------------------------------------
__global__ __launch_bounds__(256) void softmax256(const float* __restrict__ S, u16* __restrict__ A)
{
  const int tid = threadIdx.x, lane = tid & 63, wave = tid >> 6;
  const size_t row = (size_t)blockIdx.x * 4 + wave;
  const float4 v = *(const float4*)(S + row * 256 + lane * 4);
  float m = fmaxf(fmaxf(v.x, v.y), fmaxf(v.z, v.w));
#pragma unroll
  for (int o = 32; o > 0; o >>= 1) m = fmaxf(m, __shfl_xor(m, o));
  const float e0 = expf(v.x - m), e1 = expf(v.y - m), e2 = expf(v.z - m), e3 = expf(v.w - m);
  float s = e0 + e1 + e2 + e3;
#pragma unroll
  for (int o = 32; o > 0; o >>= 1) s += __shfl_xor(s, o);
  const float r = 1.0f / s;
  *(ushort4*)(A + row * 256 + lane * 4) =
      make_ushort4(f2bf(e0 * r), f2bf(e1 * r), f2bf(e2 * r), f2bf(e3 * r));
}

// ---------------------------------------------------------------------------
// Weight transpose->bf16 hi/lo from raw dtype: Wt[n][k] = W[k][n], 5 matrices.
// ---------------------------------------------------------------------------
__global__ __launch_bounds__(256) void wtrans5(
    const void* w0, const void* w1, const void* w2, const void* w3, const void* w4,
    u16* h0, u16* h1, u16* h2, u16* h3, u16* h4,
    u16* l0, u16* l1, u16* l2, u16* l3, u16* l4,
    const int* __restrict__ dflag)
{
  const int f = *dflag;
  const void* W; u16* H; u16* L;
  switch (blockIdx.z) {
    case 0: W = w0; H = h0; L = l0; break;
    case 1: W = w1; H = h1; L = l1; break;
    case 2: W = w2; H = h2; L = l2; break;
    case 3: W = w3; H = h3; L = l3; break;
    default: W = w4; H = h4; L = l4; break;
  }
  __shared__ u16 th[32][33];
  __shared__ u16 tl[32][33];
  const int tx = threadIdx.x & 31, ty = threadIdx.x >> 5;
  const int bx = blockIdx.x, by = blockIdx.y;
#pragma unroll
  for (int i = 0; i < 4; ++i) {
    const int r = ty + i * 8;
    const float v = load_in(W, ((size_t)by * 32 + r) * 1024 + bx * 32 + tx, f);
    const u16 hi = f2bf(v);
    th[r][tx] = hi;
    tl[r][tx] = f2bf(v - bf2f(hi));
  }
  __syncthreads();
#pragma unroll
  for (int i = 0; i < 4; ++i) {
    const int r = ty + i * 8;
    const size_t o = ((size_t)bx * 32 + r) * 1024 + by * 32 + tx;
    H[o] = th[tx][r];
    L[o] = tl[tx][r];
  }
}

__global__ __launch_bounds__(256) void zerof(float* p, int n)
{
  const int i = blockIdx.x * 256 + threadIdx.x;
  if (i < n) p[i] = 0.0f;
}

// ---------------------------------------------------------------------------
// BCIM phase 1: 9-offset Gram band on p2 = hi+lo. grid = (B, 8 d-splits).
// ---------------------------------------------------------------------------
__global__ __launch_bounds__(256) void bcim_dots(
    const u16* __restrict__ p2h, const u16* __restrict__ p2l, float* __restrict__ G)
{
  const int b = blockIdx.x, ds = blockIdx.y;
  __shared__ float T[512][17];
  float acc[9] = {0, 0, 0, 0, 0, 0, 0, 0, 0};
  const int tid = threadIdx.x;
  const int px = tid & 15, py = tid >> 4;
  for (int ch = 0; ch < 8; ++ch) {
    const int d0 = ds * 128 + ch * 16;
#pragma unroll
    for (int i = 0; i < 8; ++i) {
      const int j = i * 256 + tid;
      const int r = j >> 2, q4 = j & 3;
      const size_t base = ((size_t)b * 512 + r) * 1024 + d0 + q4 * 4;
      const ushort4 hv = *(const ushort4*)(p2h + base);
      const ushort4 lv = *(const ushort4*)(p2l + base);
      T[r][q4 * 4 + 0] = bf2f(hv.x) + bf2f(lv.x);
      T[r][q4 * 4 + 1] = bf2f(hv.y) + bf2f(lv.y);
      T[r][q4 * 4 + 2] = bf2f(hv.z) + bf2f(lv.z);
      T[r][q4 * 4 + 3] = bf2f(hv.w) + bf2f(lv.w);
    }
    __syncthreads();
    float a0[16], a1[16];
#pragma unroll
    for (int dc = 0; dc < 16; ++dc) { a0[dc] = T[tid][dc]; a1[dc] = T[tid + 256][dc]; }
#pragma unroll
    for (int o = 0; o < 9; ++o) {
      const int dy = o / 3 - 1, dx = o % 3 - 1;
      const int qx = px + dx, qy = py + dy;
      if (qx >= 0 && qx < 16 && qy >= 0 && qy < 16) {
        const int qp = qy * 16 + qx;
        float sum = 0.0f;
#pragma unroll
        for (int dc = 0; dc < 16; ++dc)
          sum += a0[dc] * T[qp][dc] + a1[dc] * T[qp + 256][dc];
        acc[o] += sum;
      }
    }
    __syncthreads();
  }
#pragma unroll
  for (int o = 0; o < 9; ++o)
    atomicAdd(&G[((size_t)b * 9 + o) * 256 + tid], acc[o]);
}

// BCIM phase 2: sim[b][pix]
__global__ __launch_bounds__(256) void bcim_sim_k(const float* __restrict__ G, float* __restrict__ sim)
{
  const int b = blockIdx.x, tid = threadIdx.x;
  __shared__ float nrm[256];
  const float nv = sqrtf(G[((size_t)b * 9 + 4) * 256 + tid]);
  nrm[tid] = nv;
  __syncthreads();
  const int px = tid & 15, py = tid >> 4;
  float s = 0.0f;
#pragma unroll
  for (int o = 0; o < 9; ++o) {
    const int dy = o / 3 - 1, dx = o % 3 - 1;
    const int qx = px + dx, qy = py + dy;
    if (qx >= 0 && qx < 16 && qy >= 0 && qy < 16)
      s += G[((size_t)b * 9 + o) * 256 + tid] / (nv * nrm[qy * 16 + qx]);
  }
  sim[b * 256 + tid] = s * (1.0f / 9.0f);
}

// BCIM phase 3: out[b,n,d] = (p2h+p2l)[b,n,d] * sim[b][n&255]  (f32 out)
__global__ __launch_bounds__(256) void bcim_scale(
    const u16* __restrict__ p2h, const u16* __restrict__ p2l,
    const float* __restrict__ sim, float* __restrict__ out)
{
  const size_t i4 = (size_t)blockIdx.x * 256 + threadIdx.x;
  const size_t base = i4 * 4;
  const ushort4 hv = *(const ushort4*)(p2h + base);
  const ushort4 lv = *(const ushort4*)(p2l + base);
  const size_t n = base >> 10;
  const size_t b = n >> 9;
  const int pix = (int)(n & 255);
  const float s = sim[b * 256 + pix];
  *(float4*)(out + base) = make_float4(
      (bf2f(hv.x) + bf2f(lv.x)) * s, (bf2f(hv.y) + bf2f(lv.y)) * s,
      (bf2f(hv.z) + bf2f(lv.z)) * s, (bf2f(hv.w) + bf2f(lv.w)) * s);
}

// ---------------------------------------------------------------------------
extern "C" void kernel_launch(void* const* d_in, const int* in_sizes, int n_in,
                              void* d_out, int out_size, void* d_ws, size_t ws_size,
                              hipStream_t stream)
{
  (void)in_sizes; (void)n_in; (void)out_size; (void)ws_size;
  const void* p_vector      = d_in[0];
  const void* object_vector = d_in[1];
  const void* ln_p_g = d_in[2];
  const void* ln_p_b = d_in[3];
  const void* ln_o_g = d_in[4];
  const void* ln_o_b = d_in[5];
  const void* Wq = d_in[6];  const void* bq = d_in[7];
  const void* Wk = d_in[8];  const void* bk = d_in[9];
  const void* Wv = d_in[10]; const void* bv = d_in[11];
  const void* W1 = d_in[12]; const void* b1 = d_in[13];
  const void* ln1_g = d_in[14]; const void* ln1_b = d_in[15];
  const void* W2 = d_in[16]; const void* b2 = d_in[17];
  const void* ln2_g = d_in[18]; const void* ln2_b = d_in[19];
  float* out = (float*)d_out;

  char* ws = (char*)d_ws;
  size_t off = 0;
  auto alloc = [&](size_t bytes) -> void* {
    void* p = ws + off;
    off += (bytes + 255) & ~(size_t)255;
    return p;
  };
  int* dflag = (int*)alloc(256);
  u16* WqH = (u16*)alloc((size_t)D_DIM * D_DIM * 2);
  u16* WkH = (u16*)alloc((size_t)D_DIM * D_DIM * 2);
  u16* WvH = (u16*)alloc((size_t)D_DIM * D_DIM * 2);
  u16* W1H = (u16*)alloc((size_t)D_DIM * D_DIM * 2);
  u16* W2H = (u16*)alloc((size_t)D_DIM * D_DIM * 2);
  u16* WqL = (u16*)alloc((size_t)D_DIM * D_DIM * 2);
  u16* WkL = (u16*)alloc((size_t)D_DIM * D_DIM * 2);
  u16* WvL = (u16*)alloc((size_t)D_DIM * D_DIM * 2);
  u16* W1L = (u16*)alloc((size_t)D_DIM * D_DIM * 2);
  u16* W2L = (u16*)alloc((size_t)D_DIM * D_DIM * 2);
  u16* PH = (u16*)alloc((size_t)BN * D_DIM * 2);   // pn_hi -> p1_hi -> p2_hi
  u16* PL = (u16*)alloc((size_t)BN * D_DIM * 2);   // pn_lo -> p1_lo -> p2_lo
  u16* QH = (u16*)alloc((size_t)BN * D_DIM * 2);   // q_hi -> y1 -> y2
  u16* QL = (u16*)alloc((size_t)BN * D_DIM * 2);   // q_lo -> h1
  float* S_f = (float*)alloc((size_t)BN * M_DIM * 4);
  u16* A_b   = (u16*)alloc((size_t)BN * M_DIM * 2);
  u16* onH = (u16*)alloc((size_t)M_DIM * D_DIM * 2);
  u16* onL = (u16*)alloc((size_t)M_DIM * D_DIM * 2);
  u16* kH  = (u16*)alloc((size_t)M_DIM * D_DIM * 2);
  u16* kL  = (u16*)alloc((size_t)M_DIM * D_DIM * 2);
  u16* vT  = (u16*)alloc((size_t)D_DIM * M_DIM * 2);
  float* G   = (float*)alloc((size_t)B_IMG * 9 * 256 * 4);
  float* sim = (float*)alloc((size_t)B_IMG * 256 * 4);

  // 0. dtype detect, weight transposes (hi/lo), zero G
  detect_dtype<<<1, 64, 0, stream>>>((const u16*)p_vector, dflag);
  wtrans5<<<dim3(32, 32, 5), 256, 0, stream>>>(Wq, Wk, Wv, W1, W2,
      WqH, WkH, WvH, W1H, W2H, WqL, WkL, WvL, W1L, W2L, dflag);
  zerof<<<(B_IMG * 9 * 256 + 255) / 256, 256, 0, stream>>>(G, B_IMG * 9 * 256);

  // 1. LayerNorms -> hi/lo pairs
  ln_row<<<BN, 256, 0, stream>>>(p_vector, ln_p_g, ln_p_b, dflag, PH, PL);
  ln_row<<<M_DIM, 256, 0, stream>>>(object_vector, ln_o_g, ln_o_b, dflag, onH, onL);

  // 2. k (hi/lo), v^T on 128^2 kernel (R=256); q on fine-phase 256^2 pipeline
  gemm_bt<4><<<dim3(2, 8), 256, 0, stream>>>(onH, onL, onH, WkH, WkH, WkL,
      bk, dflag, 2, 1, nullptr, nullptr, nullptr, kH, kL, M_DIM, D_DIM, D_DIM);
  gemm_bt<3><<<dim3(2, 8), 256, 0, stream>>>(onH, onL, onH, WvH, WvH, WvL,
      bv, dflag, 2, 1, nullptr, nullptr, nullptr, vT, nullptr, M_DIM, D_DIM, D_DIM);
  gemm256<4><<<dim3(128, 4), 512, 131072, stream>>>(PH, PL, PH, WqH, WqH, WqL,
      bq, dflag, 2, 1, nullptr, nullptr, nullptr, QH, QL, BN, D_DIM, D_DIM);

  // 3. S = (q_hi+q_lo)(k_hi+k_lo)^T on 128^2 kernel (NC=256: full-grid);
  //    softmax -> A bf16
  gemm_bt<1><<<dim3(256, 2), 256, 0, stream>>>(QH, QL, QH, kH, kH, kL,
      nullptr, dflag, 3, 0, nullptr, nullptr, S_f, nullptr, nullptr, BN, D_DIM, M_DIM);
  softmax256<<<BN / 4, 256, 0, stream>>>(S_f, A_b);

  // 4. p1 = pn + A v  (in-place hi/lo over PH/PL)
  gemm256<2><<<dim3(128, 4), 512, 131072, stream>>>(A_b, nullptr, nullptr, vT, nullptr, nullptr,
      nullptr, dflag, 1, 0, PH, PL, nullptr, PH, PL, BN, M_DIM, D_DIM);

  // 5. y1 = p1_hi W1 + b1 -> QH ; h1 = gelu(LN(y1)) -> QL
  gemm256<0><<<dim3(128, 4), 512, 131072, stream>>>(PH, nullptr, nullptr, W1H, nullptr, nullptr,
      b1, dflag, 1, 0, nullptr, nullptr, nullptr, QH, nullptr, BN, D_DIM, D_DIM);
  ln_gelu<0><<<BN, 256, 0, stream>>>(QH, ln1_g, ln1_b, dflag, nullptr, nullptr, QL, nullptr, nullptr);

  // 6. y2 = h1 W2 + b2 -> QH ; p2 = p1 + gelu(LN(y2)) (in-place hi/lo)
  gemm256<0><<<dim3(128, 4), 512, 131072, stream>>>(QL, nullptr, nullptr, W2H, nullptr, nullptr,
      b2, dflag, 1, 0, nullptr, nullptr, nullptr, QH, nullptr, BN, D_DIM, D_DIM);
  ln_gelu<1><<<BN, 256, 0, stream>>>(QH, ln2_g, ln2_b, dflag, PH, PL, nullptr, PH, PL);

  // 7. BCIM
  bcim_dots<<<dim3(B_IMG, 8), 256, 0, stream>>>(PH, PL, G);
  bcim_sim_k<<<B_IMG, 256, 0, stream>>>(G, sim);
  bcim_scale<<<(BN * D_DIM / 4) / 256, 256, 0, stream>>>(PH, PL, sim, out);
}

// Round 3
// 1385.155 us; speedup vs baseline: 1.1303x; 1.1301x over previous
//
#include <hip/hip_runtime.h>
#include <math.h>

#define D_DIM 1024
#define M_DIM 256
#define B_IMG 64
#define N_TOK 512
#define BN    32768

typedef unsigned short u16;
typedef __attribute__((ext_vector_type(8))) __bf16 bf16x8;
typedef __attribute__((ext_vector_type(4))) float  f32x4;

__device__ __forceinline__ u16 f2bf(float f) {
  union { float f; unsigned u; } c; c.f = f;
  unsigned u = c.u;
  return (u16)((u + 0x7FFFu + ((u >> 16) & 1u)) >> 16);
}
__device__ __forceinline__ float bf2f(u16 h) {
  union { unsigned u; float f; } c; c.u = ((unsigned)h) << 16;
  return c.f;
}

// ---------------------------------------------------------------------------
// Input-dtype detector. flag: 0 = inputs are bf16, 1 = inputs are f32.
// ---------------------------------------------------------------------------
__global__ __launch_bounds__(64) void detect_dtype(const u16* __restrict__ p, int* __restrict__ dflag)
{
  const int lane = threadIdx.x;
  const float a = fabsf(bf2f(p[lane * 2]));
  const bool sane = (a >= 1e-20f && a <= 1e3f);
  const unsigned long long m = __ballot(sane);
  if (lane == 0) *dflag = (m == ~0ull) ? 0 : 1;
}

__device__ __forceinline__ float load_in(const void* p, size_t i, int f) {
  return f ? ((const float*)p)[i] : bf2f(((const u16*)p)[i]);
}

// ---------------------------------------------------------------------------
// 128x128 multi-pass GEMM — proven round-0 kernel (y1, y2, AV, S).
// EPI: 0 bf16, 1 f32, 2 res+hi/lo, 3 bf16 transposed, 4 hi/lo split.
// ---------------------------------------------------------------------------
template<int EPI>
__global__ __launch_bounds__(256) void gemm_bt(
    const u16* __restrict__ X0, const u16* __restrict__ X1, const u16* __restrict__ X2,
    const u16* __restrict__ Bt0, const u16* __restrict__ Bt1, const u16* __restrict__ Bt2,
    const void* __restrict__ bias, const int* __restrict__ dflag,
    int np_base, int np_extra,
    const u16* res_hi, const u16* res_lo,
    float* outf, u16* outb, u16* outb2,
    int R, int K, int NC)
{
  __shared__ u16 lA[128 * 64];
  __shared__ u16 lB[128 * 64];
  const int tid  = threadIdx.x;
  const int wave = tid >> 6, lane = tid & 63;
  const int quad = lane >> 4, l15 = lane & 15;
  const int wr = wave & 1, wc = wave >> 1;
  const int rblk = blockIdx.x, cblk = blockIdx.y;

  const int np = np_base + (np_extra ? np_extra * (*dflag) : 0);

  const int srow = lane >> 3;
  const int scol = ((lane & 7) ^ (srow & 7)) * 8;

  const u16* Xs[3] = {X0, X1, X2};
  const u16* Bs[3] = {Bt0, Bt1, Bt2};

  f32x4 acc[4][4] = {};

  for (int p = 0; p < np; ++p) {
    const u16* gA = Xs[p] + (size_t)(rblk * 128 + srow) * K + scol;
    const u16* gB = Bs[p] + (size_t)(cblk * 128 + srow) * K + scol;
    for (int k0 = 0; k0 < K; k0 += 64) {
#pragma unroll
      for (int i = 0; i < 4; ++i) {
        const int j = i * 4 + wave;
        __builtin_amdgcn_global_load_lds(
            (const __attribute__((address_space(1))) void*)(gA + (size_t)j * 8 * K + k0),
            (__attribute__((address_space(3))) void*)(lA + j * 512), 16, 0, 0);
        __builtin_amdgcn_global_load_lds(
            (const __attribute__((address_space(1))) void*)(gB + (size_t)j * 8 * K + k0),
            (__attribute__((address_space(3))) void*)(lB + j * 512), 16, 0, 0);
      }
      __syncthreads();
#pragma unroll
      for (int s = 0; s < 2; ++s) {
        bf16x8 af[4], bfr[4];
#pragma unroll
        for (int r = 0; r < 4; ++r) {
          const int row  = wr * 64 + r * 16 + l15;
          const int slot = (s * 4 + quad) ^ (row & 7);
          af[r] = *(const bf16x8*)(lA + row * 64 + slot * 8);
        }
#pragma unroll
        for (int c = 0; c < 4; ++c) {
          const int row  = wc * 64 + c * 16 + l15;
          const int slot = (s * 4 + quad) ^ (row & 7);
          bfr[c] = *(const bf16x8*)(lB + row * 64 + slot * 8);
        }
#pragma unroll
        for (int r = 0; r < 4; ++r)
#pragma unroll
          for (int c = 0; c < 4; ++c)
            acc[r][c] = __builtin_amdgcn_mfma_f32_16x16x32_bf16(af[r], bfr[c], acc[r][c], 0, 0, 0);
      }
      __syncthreads();
    }
  }

  const int fdt = bias ? *dflag : 0;
  const int crow0 = rblk * 128 + wr * 64;
  const int ccol0 = cblk * 128 + wc * 64;
#pragma unroll
  for (int c = 0; c < 4; ++c) {
    const int col = ccol0 + c * 16 + l15;
    const float bcol = bias ? load_in(bias, col, fdt) : 0.0f;
#pragma unroll
    for (int r = 0; r < 4; ++r) {
#pragma unroll
      for (int t = 0; t < 4; ++t) {
        const int row = crow0 + r * 16 + quad * 4 + t;
        const size_t idx = (size_t)row * NC + col;
        float v = acc[r][c][t] + bcol;
        if (EPI == 0) {
          outb[idx] = f2bf(v);
        } else if (EPI == 1) {
          outf[idx] = v;
        } else if (EPI == 2) {
          const float p = bf2f(res_hi[idx]) + bf2f(res_lo[idx]) + v;
          const u16 hi = f2bf(p);
          outb[idx]  = hi;
          outb2[idx] = f2bf(p - bf2f(hi));
        } else if (EPI == 3) {
          outb[(size_t)col * R + row] = f2bf(v);
        } else {  // EPI 4: hi/lo split
          const u16 hi = f2bf(v);
          outb[idx]  = hi;
          outb2[idx] = f2bf(v - bf2f(hi));
        }
      }
    }
  }
}

// ---------------------------------------------------------------------------
// Merged k+v projection: z=0 -> k = LN(o)W_k + b_k (hi/lo split out kh/kl),
// z=1 -> vT = (LN(o)W_v + b_v)^T. Same 128^2 tile machinery as gemm_bt;
// merging the two 16-block latency-bound dispatches halves their wall time.
// R=256, K=1024, NC=1024. grid (2, 8, 2).
// ---------------------------------------------------------------------------
__global__ __launch_bounds__(256) void gemm_kv(
    const u16* __restrict__ on_h, const u16* __restrict__ on_l,
    const u16* __restrict__ WkH_, const u16* __restrict__ WkL_,
    const u16* __restrict__ WvH_, const u16* __restrict__ WvL_,
    const void* __restrict__ bk_, const void* __restrict__ bv_,
    const int* __restrict__ dflag,
    u16* __restrict__ kh, u16* __restrict__ kl, u16* __restrict__ vt)
{
  __shared__ u16 lA[128 * 64];
  __shared__ u16 lB[128 * 64];
  const int tid  = threadIdx.x;
  const int wave = tid >> 6, lane = tid & 63;
  const int quad = lane >> 4, l15 = lane & 15;
  const int wr = wave & 1, wc = wave >> 1;
  const int rblk = blockIdx.x, cblk = blockIdx.y;
  const int zv = blockIdx.z;
  const int K = D_DIM, NC = D_DIM, R = M_DIM;

  const int np = 2 + *dflag;

  const int srow = lane >> 3;
  const int scol = ((lane & 7) ^ (srow & 7)) * 8;

  const u16* Xs[3] = {on_h, on_l, on_h};
  const u16* Bs[3];
  if (zv == 0) { Bs[0] = WkH_; Bs[1] = WkH_; Bs[2] = WkL_; }
  else         { Bs[0] = WvH_; Bs[1] = WvH_; Bs[2] = WvL_; }
  const void* bias = zv == 0 ? bk_ : bv_;

  f32x4 acc[4][4] = {};

  for (int p = 0; p < np; ++p) {
    const u16* gA = Xs[p] + (size_t)(rblk * 128 + srow) * K + scol;
    const u16* gB = Bs[p] + (size_t)(cblk * 128 + srow) * K + scol;
    for (int k0 = 0; k0 < K; k0 += 64) {
#pragma unroll
      for (int i = 0; i < 4; ++i) {
        const int j = i * 4 + wave;
        __builtin_amdgcn_global_load_lds(
            (const __attribute__((address_space(1))) void*)(gA + (size_t)j * 8 * K + k0),
            (__attribute__((address_space(3))) void*)(lA + j * 512), 16, 0, 0);
        __builtin_amdgcn_global_load_lds(
            (const __attribute__((address_space(1))) void*)(gB + (size_t)j * 8 * K + k0),
            (__attribute__((address_space(3))) void*)(lB + j * 512), 16, 0, 0);
      }
      __syncthreads();
#pragma unroll
      for (int s = 0; s < 2; ++s) {
        bf16x8 af[4], bfr[4];
#pragma unroll
        for (int r = 0; r < 4; ++r) {
          const int row  = wr * 64 + r * 16 + l15;
          const int slot = (s * 4 + quad) ^ (row & 7);
          af[r] = *(const bf16x8*)(lA + row * 64 + slot * 8);
        }
#pragma unroll
        for (int c = 0; c < 4; ++c) {
          const int row  = wc * 64 + c * 16 + l15;
          const int slot = (s * 4 + quad) ^ (row & 7);
          bfr[c] = *(const bf16x8*)(lB + row * 64 + slot * 8);
        }
#pragma unroll
        for (int r = 0; r < 4; ++r)
#pragma unroll
          for (int c = 0; c < 4; ++c)
            acc[r][c] = __builtin_amdgcn_mfma_f32_16x16x32_bf16(af[r], bfr[c], acc[r][c], 0, 0, 0);
      }
      __syncthreads();
    }
  }

  const int fdt = *dflag;
  const int crow0 = rblk * 128 + wr * 64;
  const int ccol0 = cblk * 128 + wc * 64;
#pragma unroll
  for (int c = 0; c < 4; ++c) {
    const int col = ccol0 + c * 16 + l15;
    const float bcol = load_in(bias, col, fdt);
#pragma unroll
    for (int r = 0; r < 4; ++r) {
#pragma unroll
      for (int t = 0; t < 4; ++t) {
        const int row = crow0 + r * 16 + quad * 4 + t;
        float v = acc[r][c][t] + bcol;
        if (zv == 0) {
          const size_t idx = (size_t)row * NC + col;
          const u16 hi = f2bf(v);
          kh[idx] = hi;
          kl[idx] = f2bf(v - bf2f(hi));
        } else {
          vt[(size_t)col * R + row] = f2bf(v);
        }
      }
    }
  }
}

// ---------------------------------------------------------------------------
// 256x256-tile 8-wave GEMM, fine-phase pipeline, 3-deep prefetch:
// BK=32 K-tiles in a 4-slot LDS ring (4 x 32 KiB = 128 KiB). Per tile, two
// phases: {ds_read frags, stage tile t+3 (ph0), barrier, lgkmcnt(0),
// 16 MFMA, barrier}. One counted s_waitcnt vmcnt(8) per tile (never 0 in
// the loop): per-wave FIFO at tile t ph1 = [t+1:4][t+2:4][t+3:4]; vmcnt(8)
// drains tile t+1, issued at tile t-2 ph0 (~5.5 phases earlier) -> HBM
// latency fully covered. WAR safety: slot (t+3)&3 was last read at tile
// t-1, whose reads complete before t-1's closing barrier, which precedes
// the stage issue. Tail stages clamp the source index but keep the
// slot/wait/barrier structure uniform; a final vmcnt(0) drains the dead
// clamped prefetches before exit (they target slots 0-2 of the NEXT block
// on this CU otherwise). Grid is (cblk, rblk) = (4, 128) so the 4 blocks
// sharing an A-panel are launch-adjacent (co-resident across XCDs).
// EPI: 0 bf16, 1 f32, 2 res+hi/lo, 4 hi/lo split.
// ---------------------------------------------------------------------------
template<int EPI>
__global__ __launch_bounds__(512, 2) void gemm256(
    const u16* __restrict__ X0, const u16* __restrict__ X1, const u16* __restrict__ X2,
    const u16* __restrict__ Bt0, const u16* __restrict__ Bt1, const u16* __restrict__ Bt2,
    const void* __restrict__ bias, const int* __restrict__ dflag,
    int np_base, int np_extra,
    const u16* res_hi, const u16* res_lo,
    float* outf, u16* outb, u16* outb2,
    int R, int K, int NC)
{
  extern __shared__ u16 lds2[];   // 4 slots x (A 256x32 | B 256x32) u16
  const int tid  = threadIdx.x;
  const int wave = tid >> 6, lane = tid & 63;
  const int quad = lane >> 4, l15 = lane & 15;
  const int wm = wave >> 2, wn = wave & 3;     // 2x4 wave grid
  const int rblk = blockIdx.y, cblk = blockIdx.x;   // flipped grid

  const int np = np_base + (np_extra ? np_extra * (*dflag) : 0);
  const int ktiles = K >> 5;                    // BK=32 tiles per pass (pow2)
  const int ktl = 31 - __builtin_clz(ktiles);
  const int NT = np << ktl;

  const u16* Xs[3] = {X0, X1, X2};
  const u16* Bs[3] = {Bt0, Bt1, Bt2};

  // staging: one gload covers 16 rows x 4 slots (lane -> row lane>>2,
  // phys slot lane&3). Source col-group pre-swizzled so LDS phys slot s of
  // row r holds logical group s ^ ((r>>1)&3)  (self-inverse).
  const int srow  = lane >> 2;
  const int sslot = lane & 3;

  f32x4 acc[8][4] = {};

  auto stage_tile = [&](int t) {
    const int tc = t < NT ? t : NT - 1;        // clamp (uniform tail)
    const int p  = tc >> ktl;
    const int k0 = (tc & (ktiles - 1)) << 5;
    u16* dst = lds2 + (t & 3) * 16384;         // 32 KiB slot (in u16)
#pragma unroll
    for (int i = 0; i < 2; ++i) {
      const int rbase = wave * 32 + i * 16;
      const int r  = rbase + srow;
      const int cg = (sslot ^ ((r >> 1) & 3)) * 8;
      __builtin_amdgcn_global_load_lds(
          (const __attribute__((address_space(1))) void*)(Xs[p] + (size_t)(rblk * 256 + r) * K + k0 + cg),
          (__attribute__((address_space(3))) void*)(dst + rbase * 32), 16, 0, 0);
    }
#pragma unroll
    for (int i = 0; i < 2; ++i) {
      const int rbase = wave * 32 + i * 16;
      const int r  = rbase + srow;
      const int cg = (sslot ^ ((r >> 1) & 3)) * 8;
      __builtin_amdgcn_global_load_lds(
          (const __attribute__((address_space(1))) void*)(Bs[p] + (size_t)(cblk * 256 + r) * K + k0 + cg),
          (__attribute__((address_space(3))) void*)(dst + 8192 + rbase * 32), 16, 0, 0);
    }
  };

  // prologue: tiles 0,1,2 staged (12 loads); confirm tile 0 (vmcnt(8)),
  // keep tiles 1,2 in flight
  stage_tile(0);
  stage_tile(1);
  stage_tile(2);
  asm volatile("s_waitcnt vmcnt(8)" ::: "memory");
  __builtin_amdgcn_s_barrier();

  for (int t = 0; t < NT; ++t) {
    const u16* bufA = lds2 + (t & 3) * 16384;
    const u16* bufB = bufA + 8192;
    bf16x8 bfr[4], af[4];
    // ---- phase 0: B frags (4) + A frags m0-3 (4); stage tile t+3 ----
#pragma unroll
    for (int n = 0; n < 4; ++n) {
      const int row = wn * 64 + n * 16 + l15;
      const int ps  = quad ^ ((row >> 1) & 3);
      bfr[n] = *(const bf16x8*)(bufB + row * 32 + ps * 8);
    }
#pragma unroll
    for (int m = 0; m < 4; ++m) {
      const int row = wm * 128 + m * 16 + l15;
      const int ps  = quad ^ ((row >> 1) & 3);
      af[m] = *(const bf16x8*)(bufA + row * 32 + ps * 8);
    }
    stage_tile(t + 3);
    __builtin_amdgcn_s_barrier();
    asm volatile("s_waitcnt lgkmcnt(0)" ::: "memory");
    __builtin_amdgcn_s_setprio(1);
#pragma unroll
    for (int m = 0; m < 4; ++m)
#pragma unroll
      for (int n = 0; n < 4; ++n)
        acc[m][n] = __builtin_amdgcn_mfma_f32_16x16x32_bf16(af[m], bfr[n], acc[m][n], 0, 0, 0);
    __builtin_amdgcn_s_setprio(0);
    __builtin_amdgcn_s_barrier();
    // ---- phase 1: A frags m4-7 (4); counted vmcnt for tile t+1 ----
#pragma unroll
    for (int m = 0; m < 4; ++m) {
      const int row = wm * 128 + 64 + m * 16 + l15;
      const int ps  = quad ^ ((row >> 1) & 3);
      af[m] = *(const bf16x8*)(bufA + row * 32 + ps * 8);
    }
    asm volatile("s_waitcnt vmcnt(8)" ::: "memory");
    __builtin_amdgcn_s_barrier();
    asm volatile("s_waitcnt lgkmcnt(0)" ::: "memory");
    __builtin_amdgcn_s_setprio(1);
#pragma unroll
    for (int m = 0; m < 4; ++m)
#pragma unroll
      for (int n = 0; n < 4; ++n)
        acc[4 + m][n] = __builtin_amdgcn_mfma_f32_16x16x32_bf16(af[m], bfr[n], acc[4 + m][n], 0, 0, 0);
    __builtin_amdgcn_s_setprio(0);
    __builtin_amdgcn_s_barrier();
  }
  // drain dead clamped prefetches: their LDS writes must not land in the
  // next block's freshly-staged prologue slots on this CU.
  asm volatile("s_waitcnt vmcnt(0)" ::: "memory");

  const int fdt = bias ? *dflag : 0;
  const int crow0 = rblk * 256 + wm * 128;
  const int ccol0 = cblk * 256 + wn * 64;
#pragma unroll
  for (int n = 0; n < 4; ++n) {
    const int col = ccol0 + n * 16 + l15;
    const float bcol = bias ? load_in(bias, col, fdt) : 0.0f;
#pragma unroll
    for (int m = 0; m < 8; ++m) {
#pragma unroll
      for (int u = 0; u < 4; ++u) {
        const int row = crow0 + m * 16 + quad * 4 + u;
        const size_t idx = (size_t)row * NC + col;
        float v = acc[m][n][u] + bcol;
        if (EPI == 0) {
          outb[idx] = f2bf(v);
        } else if (EPI == 1) {
          outf[idx] = v;
        } else if (EPI == 2) {
          const float pp = bf2f(res_hi[idx]) + bf2f(res_lo[idx]) + v;
          const u16 hi = f2bf(pp);
          outb[idx]  = hi;
          outb2[idx] = f2bf(pp - bf2f(hi));
        } else {  // EPI 4
          const u16 hi = f2bf(v);
          outb[idx]  = hi;
          outb2[idx] = f2bf(v - bf2f(hi));
        }
      }
    }
  }
}

// ---------------------------------------------------------------------------
// LayerNorm over D=1024 on raw input (dtype via flag); writes hi/lo bf16 pair.
// ---------------------------------------------------------------------------
__global__ __launch_bounds__(256) void ln_row(
    const void* __restrict__ x, const void* __restrict__ g, const void* __restrict__ b,
    const int* __restrict__ dflag, u16* __restrict__ oh, u16* __restrict__ ol)
{
  const int f = *dflag;
  const int row = blockIdx.x, tid = threadIdx.x;
  const int col = tid * 4;
  const size_t base = (size_t)row * 1024 + col;
  float v0, v1, v2, v3;
  if (f) {
    const float4 xv = *(const float4*)((const float*)x + base);
    v0 = xv.x; v1 = xv.y; v2 = xv.z; v3 = xv.w;
  } else {
    const ushort4 xv = *(const ushort4*)((const u16*)x + base);
    v0 = bf2f(xv.x); v1 = bf2f(xv.y); v2 = bf2f(xv.z); v3 = bf2f(xv.w);
  }
  float s  = v0 + v1 + v2 + v3;
  float sq = v0 * v0 + v1 * v1 + v2 * v2 + v3 * v3;
#pragma unroll
  for (int o = 32; o > 0; o >>= 1) { s += __shfl_xor(s, o); sq += __shfl_xor(sq, o); }
  __shared__ float red[8];
  if ((tid & 63) == 0) { red[tid >> 6] = s; red[4 + (tid >> 6)] = sq; }
  __syncthreads();
  s  = red[0] + red[1] + red[2] + red[3];
  sq = red[4] + red[5] + red[6] + red[7];
  const float mean = s * (1.0f / 1024.0f);
  const float var  = sq * (1.0f / 1024.0f) - mean * mean;
  const float rs   = rsqrtf(var + 1e-5f);
  float y[4];
  y[0] = (v0 - mean) * rs * load_in(g, col + 0, f) + load_in(b, col + 0, f);
  y[1] = (v1 - mean) * rs * load_in(g, col + 1, f) + load_in(b, col + 1, f);
  y[2] = (v2 - mean) * rs * load_in(g, col + 2, f) + load_in(b, col + 2, f);
  y[3] = (v3 - mean) * rs * load_in(g, col + 3, f) + load_in(b, col + 3, f);
  ushort4 hv, lv;
  hv.x = f2bf(y[0]); lv.x = f2bf(y[0] - bf2f(hv.x));
  hv.y = f2bf(y[1]); lv.y = f2bf(y[1] - bf2f(hv.y));
  hv.z = f2bf(y[2]); lv.z = f2bf(y[2] - bf2f(hv.z));
  hv.w = f2bf(y[3]); lv.w = f2bf(y[3] - bf2f(hv.w));
  *(ushort4*)(oh + base) = hv;
  *(ushort4*)(ol + base) = lv;
}

// ---------------------------------------------------------------------------
// LN + exact GELU on internal bf16 input; g/b raw dtype.
// MODE 0: write gelu bf16 (ob). MODE 1: p = res_hi+res_lo + gelu, hi/lo out.
// ---------------------------------------------------------------------------
template<int MODE>
__global__ __launch_bounds__(256) void ln_gelu(
    const u16* __restrict__ x, const void* __restrict__ g, const void* __restrict__ b,
    const int* __restrict__ dflag,
    const u16* res_hi, const u16* res_lo,
    u16* ob, u16* oh, u16* ol)
{
  const int f = *dflag;
  const int row = blockIdx.x, tid = threadIdx.x;
  const int col = tid * 4;
  const size_t base = (size_t)row * 1024 + col;
  const ushort4 xv = *(const ushort4*)(x + base);
  const float v0 = bf2f(xv.x), v1 = bf2f(xv.y), v2 = bf2f(xv.z), v3 = bf2f(xv.w);
  float s  = v0 + v1 + v2 + v3;
  float sq = v0 * v0 + v1 * v1 + v2 * v2 + v3 * v3;
#pragma unroll
  for (int o = 32; o > 0; o >>= 1) { s += __shfl_xor(s, o); sq += __shfl_xor(sq, o); }
  __shared__ float red[8];
  if ((tid & 63) == 0) { red[tid >> 6] = s; red[4 + (tid >> 6)] = sq; }
  __syncthreads();
  s  = red[0] + red[1] + red[2] + red[3];
  sq = red[4] + red[5] + red[6] + red[7];
  const float mean = s * (1.0f / 1024.0f);
  const float var  = sq * (1.0f / 1024.0f) - mean * mean;
  const float rs   = rsqrtf(var + 1e-5f);
  float z[4], h[4];
  z[0] = (v0 - mean) * rs * load_in(g, col + 0, f) + load_in(b, col + 0, f);
  z[1] = (v1 - mean) * rs * load_in(g, col + 1, f) + load_in(b, col + 1, f);
  z[2] = (v2 - mean) * rs * load_in(g, col + 2, f) + load_in(b, col + 2, f);
  z[3] = (v3 - mean) * rs * load_in(g, col + 3, f) + load_in(b, col + 3, f);
#pragma unroll
  for (int i = 0; i < 4; ++i)
    h[i] = 0.5f * z[i] * (1.0f + erff(z[i] * 0.70710678118654752f));
  if (MODE == 0) {
    *(ushort4*)(ob + base) = make_ushort4(f2bf(h[0]), f2bf(h[1]), f2bf(h[2]), f2bf(h[3]));
  } else {
    const ushort4 rh = *(const ushort4*)(res_hi + base);
    const ushort4 rl = *(const ushort4*)(res_lo + base);
    float p[4];
    p[0] = bf2f(rh.x) + bf2f(rl.x) + h[0];
    p[1] = bf2f(rh.y) + bf2f(rl.y) + h[1];
    p[2] = bf2f(rh.z) + bf2f(rl.z) + h[2];
    p[3] = bf2f(rh.w) + bf2f(rl.w) + h[3];
    ushort4 hv, lv;
    hv.x = f2bf(p[0]); lv.x = f2bf(p[0] - bf2f(hv.x));
    hv.y = f2bf(p[1]); lv.y = f2bf(p[1] - bf2f(hv.y));
    hv.z = f2bf(p[2]); lv.z = f2bf(p[2] - bf2f(hv.z));
    hv.w = f2bf(p[3]); lv.w = f2bf(p[3] - bf2f(hv.w));
    *(ushort4*)(oh + base) = hv;
    *(ushort4*)(ol + base) = lv;
  }
}

// ---------------------------------------------------------------------------
// Softmax over M=256; one wave per row, 4 rows per block. f32 in, bf16 out.
// ---------------------------------------------------------------------------
__global__ __launch_bounds__(256) void softmax256(const float* __restrict__ S, u16* __restrict__ A)
{
  const int tid = threadIdx.x, lane = tid & 63, wave = tid >> 6;
  const size_t row = (size_t)blockIdx.x * 4 + wave;
  const float4 v = *(const float4*)(S + row * 256 + lane * 4);
  float m = fmaxf(fmaxf(v.x, v.y), fmaxf(v.z, v.w));
#pragma unroll
  for (int o = 32; o > 0; o >>= 1) m = fmaxf(m, __shfl_xor(m, o));
  const float e0 = expf(v.x - m), e1 = expf(v.y - m), e2 = expf(v.z - m), e3 = expf(v.w - m);
  float s = e0 + e1 + e2 + e3;
#pragma unroll
  for (int o = 32; o > 0; o >>= 1) s += __shfl_xor(s, o);
  const float r = 1.0f / s;
  *(ushort4*)(A + row * 256 + lane * 4) =
      make_ushort4(f2bf(e0 * r), f2bf(e1 * r), f2bf(e2 * r), f2bf(e3 * r));
}

// ---------------------------------------------------------------------------
// Weight transpose->bf16 hi/lo from raw dtype: Wt[n][k] = W[k][n], 5 matrices.
// ---------------------------------------------------------------------------
__global__ __launch_bounds__(256) void wtrans5(
    const void* w0, const void* w1, const void* w2, const void* w3, const void* w4,
    u16* h0, u16* h1, u16* h2, u16* h3, u16* h4,
    u16* l0, u16* l1, u16* l2, u16* l3, u16* l4,
    const int* __restrict__ dflag)
{
  const int f = *dflag;
  const void* W; u16* H; u16* L;
  switch (blockIdx.z) {
    case 0: W = w0; H = h0; L = l0; break;
    case 1: W = w1; H = h1; L = l1; break;
    case 2: W = w2; H = h2; L = l2; break;
    case 3: W = w3; H = h3; L = l3; break;
    default: W = w4; H = h4; L = l4; break;
  }
  __shared__ u16 th[32][33];
  __shared__ u16 tl[32][33];
  const int tx = threadIdx.x & 31, ty = threadIdx.x >> 5;
  const int bx = blockIdx.x, by = blockIdx.y;
#pragma unroll
  for (int i = 0; i < 4; ++i) {
    const int r = ty + i * 8;
    const float v = load_in(W, ((size_t)by * 32 + r) * 1024 + bx * 32 + tx, f);
    const u16 hi = f2bf(v);
    th[r][tx] = hi;
    tl[r][tx] = f2bf(v - bf2f(hi));
  }
  __syncthreads();
#pragma unroll
  for (int i = 0; i < 4; ++i) {
    const int r = ty + i * 8;
    const size_t o = ((size_t)bx * 32 + r) * 1024 + by * 32 + tx;
    H[o] = th[tx][r];
    L[o] = tl[tx][r];
  }
}

__global__ __launch_bounds__(256) void zerof(float* p, int n)
{
  const int i = blockIdx.x * 256 + threadIdx.x;
  if (i < n) p[i] = 0.0f;
}

// ---------------------------------------------------------------------------
// BCIM phase 1: 9-offset Gram band on p2 = hi+lo. grid = (B, 8 d-splits).
// ---------------------------------------------------------------------------
__global__ __launch_bounds__(256) void bcim_dots(
    const u16* __restrict__ p2h, const u16* __restrict__ p2l, float* __restrict__ G)
{
  const int b = blockIdx.x, ds = blockIdx.y;
  __shared__ float T[512][17];
  float acc[9] = {0, 0, 0, 0, 0, 0, 0, 0, 0};
  const int tid = threadIdx.x;
  const int px = tid & 15, py = tid >> 4;
  for (int ch = 0; ch < 8; ++ch) {
    const int d0 = ds * 128 + ch * 16;
#pragma unroll
    for (int i = 0; i < 8; ++i) {
      const int j = i * 256 + tid;
      const int r = j >> 2, q4 = j & 3;
      const size_t base = ((size_t)b * 512 + r) * 1024 + d0 + q4 * 4;
      const ushort4 hv = *(const ushort4*)(p2h + base);
      const ushort4 lv = *(const ushort4*)(p2l + base);
      T[r][q4 * 4 + 0] = bf2f(hv.x) + bf2f(lv.x);
      T[r][q4 * 4 + 1] = bf2f(hv.y) + bf2f(lv.y);
      T[r][q4 * 4 + 2] = bf2f(hv.z) + bf2f(lv.z);
      T[r][q4 * 4 + 3] = bf2f(hv.w) + bf2f(lv.w);
    }
    __syncthreads();
    float a0[16], a1[16];
#pragma unroll
    for (int dc = 0; dc < 16; ++dc) { a0[dc] = T[tid][dc]; a1[dc] = T[tid + 256][dc]; }
#pragma unroll
    for (int o = 0; o < 9; ++o) {
      const int dy = o / 3 - 1, dx = o % 3 - 1;
      const int qx = px + dx, qy = py + dy;
      if (qx >= 0 && qx < 16 && qy >= 0 && qy < 16) {
        const int qp = qy * 16 + qx;
        float sum = 0.0f;
#pragma unroll
        for (int dc = 0; dc < 16; ++dc)
          sum += a0[dc] * T[qp][dc] + a1[dc] * T[qp + 256][dc];
        acc[o] += sum;
      }
    }
    __syncthreads();
  }
#pragma unroll
  for (int o = 0; o < 9; ++o)
    atomicAdd(&G[((size_t)b * 9 + o) * 256 + tid], acc[o]);
}

// BCIM phase 2: sim[b][pix]
__global__ __launch_bounds__(256) void bcim_sim_k(const float* __restrict__ G, float* __restrict__ sim)
{
  const int b = blockIdx.x, tid = threadIdx.x;
  __shared__ float nrm[256];
  const float nv = sqrtf(G[((size_t)b * 9 + 4) * 256 + tid]);
  nrm[tid] = nv;
  __syncthreads();
  const int px = tid & 15, py = tid >> 4;
  float s = 0.0f;
#pragma unroll
  for (int o = 0; o < 9; ++o) {
    const int dy = o / 3 - 1, dx = o % 3 - 1;
    const int qx = px + dx, qy = py + dy;
    if (qx >= 0 && qx < 16 && qy >= 0 && qy < 16)
      s += G[((size_t)b * 9 + o) * 256 + tid] / (nv * nrm[qy * 16 + qx]);
  }
  sim[b * 256 + tid] = s * (1.0f / 9.0f);
}

// BCIM phase 3: out[b,n,d] = (p2h+p2l)[b,n,d] * sim[b][n&255]  (f32 out)
__global__ __launch_bounds__(256) void bcim_scale(
    const u16* __restrict__ p2h, const u16* __restrict__ p2l,
    const float* __restrict__ sim, float* __restrict__ out)
{
  const size_t i4 = (size_t)blockIdx.x * 256 + threadIdx.x;
  const size_t base = i4 * 4;
  const ushort4 hv = *(const ushort4*)(p2h + base);
  const ushort4 lv = *(const ushort4*)(p2l + base);
  const size_t n = base >> 10;
  const size_t b = n >> 9;
  const int pix = (int)(n & 255);
  const float s = sim[b * 256 + pix];
  *(float4*)(out + base) = make_float4(
      (bf2f(hv.x) + bf2f(lv.x)) * s, (bf2f(hv.y) + bf2f(lv.y)) * s,
      (bf2f(hv.z) + bf2f(lv.z)) * s, (bf2f(hv.w) + bf2f(lv.w)) * s);
}

// ---------------------------------------------------------------------------
extern "C" void kernel_launch(void* const* d_in, const int* in_sizes, int n_in,
                              void* d_out, int out_size, void* d_ws, size_t ws_size,
                              hipStream_t stream)
{
  (void)in_sizes; (void)n_in; (void)out_size; (void)ws_size;
  const void* p_vector      = d_in[0];
  const void* object_vector = d_in[1];
  const void* ln_p_g = d_in[2];
  const void* ln_p_b = d_in[3];
  const void* ln_o_g = d_in[4];
  const void* ln_o_b = d_in[5];
  const void* Wq = d_in[6];  const void* bq = d_in[7];
  const void* Wk = d_in[8];  const void* bk = d_in[9];
  const void* Wv = d_in[10]; const void* bv = d_in[11];
  const void* W1 = d_in[12]; const void* b1 = d_in[13];
  const void* ln1_g = d_in[14]; const void* ln1_b = d_in[15];
  const void* W2 = d_in[16]; const void* b2 = d_in[17];
  const void* ln2_g = d_in[18]; const void* ln2_b = d_in[19];
  float* out = (float*)d_out;

  char* ws = (char*)d_ws;
  size_t off = 0;
  auto alloc = [&](size_t bytes) -> void* {
    void* p = ws + off;
    off += (bytes + 255) & ~(size_t)255;
    return p;
  };
  int* dflag = (int*)alloc(256);
  u16* WqH = (u16*)alloc((size_t)D_DIM * D_DIM * 2);
  u16* WkH = (u16*)alloc((size_t)D_DIM * D_DIM * 2);
  u16* WvH = (u16*)alloc((size_t)D_DIM * D_DIM * 2);
  u16* W1H = (u16*)alloc((size_t)D_DIM * D_DIM * 2);
  u16* W2H = (u16*)alloc((size_t)D_DIM * D_DIM * 2);
  u16* WqL = (u16*)alloc((size_t)D_DIM * D_DIM * 2);
  u16* WkL = (u16*)alloc((size_t)D_DIM * D_DIM * 2);
  u16* WvL = (u16*)alloc((size_t)D_DIM * D_DIM * 2);
  u16* W1L = (u16*)alloc((size_t)D_DIM * D_DIM * 2);
  u16* W2L = (u16*)alloc((size_t)D_DIM * D_DIM * 2);
  u16* PH = (u16*)alloc((size_t)BN * D_DIM * 2);   // pn_hi -> p1_hi -> p2_hi
  u16* PL = (u16*)alloc((size_t)BN * D_DIM * 2);   // pn_lo -> p1_lo -> p2_lo
  u16* QH = (u16*)alloc((size_t)BN * D_DIM * 2);   // q_hi -> y1 -> y2
  u16* QL = (u16*)alloc((size_t)BN * D_DIM * 2);   // q_lo -> h1
  float* S_f = (float*)alloc((size_t)BN * M_DIM * 4);
  u16* A_b   = (u16*)alloc((size_t)BN * M_DIM * 2);
  u16* onH = (u16*)alloc((size_t)M_DIM * D_DIM * 2);
  u16* onL = (u16*)alloc((size_t)M_DIM * D_DIM * 2);
  u16* kH  = (u16*)alloc((size_t)M_DIM * D_DIM * 2);
  u16* kL  = (u16*)alloc((size_t)M_DIM * D_DIM * 2);
  u16* vT  = (u16*)alloc((size_t)D_DIM * M_DIM * 2);
  float* G   = (float*)alloc((size_t)B_IMG * 9 * 256 * 4);
  float* sim = (float*)alloc((size_t)B_IMG * 256 * 4);

  // 0. dtype detect, weight transposes (hi/lo), zero G
  detect_dtype<<<1, 64, 0, stream>>>((const u16*)p_vector, dflag);
  wtrans5<<<dim3(32, 32, 5), 256, 0, stream>>>(Wq, Wk, Wv, W1, W2,
      WqH, WkH, WvH, W1H, W2H, WqL, WkL, WvL, W1L, W2L, dflag);
  zerof<<<(B_IMG * 9 * 256 + 255) / 256, 256, 0, stream>>>(G, B_IMG * 9 * 256);

  // 1. LayerNorms -> hi/lo pairs
  ln_row<<<BN, 256, 0, stream>>>(p_vector, ln_p_g, ln_p_b, dflag, PH, PL);
  ln_row<<<M_DIM, 256, 0, stream>>>(object_vector, ln_o_g, ln_o_b, dflag, onH, onL);

  // 2. k+v merged (one z-indexed dispatch); q on gemm256 3-deep pipeline
  gemm_kv<<<dim3(2, 8, 2), 256, 0, stream>>>(onH, onL, WkH, WkL, WvH, WvL,
      bk, bv, dflag, kH, kL, vT);
  gemm256<4><<<dim3(4, 128), 512, 131072, stream>>>(PH, PL, PH, WqH, WqH, WqL,
      bq, dflag, 2, 1, nullptr, nullptr, nullptr, QH, QL, BN, D_DIM, D_DIM);

  // 3. S = (q_hi+q_lo)(k_hi+k_lo)^T (3 split passes); softmax -> A bf16
  gemm_bt<1><<<dim3(256, 2), 256, 0, stream>>>(QH, QL, QH, kH, kH, kL,
      nullptr, dflag, 3, 0, nullptr, nullptr, S_f, nullptr, nullptr, BN, D_DIM, M_DIM);
  softmax256<<<BN / 4, 256, 0, stream>>>(S_f, A_b);

  // 4. p1 = pn + A v  (in-place hi/lo over PH/PL)
  gemm_bt<2><<<dim3(256, 8), 256, 0, stream>>>(A_b, nullptr, nullptr, vT, nullptr, nullptr,
      nullptr, dflag, 1, 0, PH, PL, nullptr, PH, PL, BN, M_DIM, D_DIM);

  // 5. y1 = p1_hi W1 + b1 -> QH ; h1 = gelu(LN(y1)) -> QL
  gemm_bt<0><<<dim3(256, 8), 256, 0, stream>>>(PH, nullptr, nullptr, W1H, nullptr, nullptr,
      b1, dflag, 1, 0, nullptr, nullptr, nullptr, QH, nullptr, BN, D_DIM, D_DIM);
  ln_gelu<0><<<BN, 256, 0, stream>>>(QH, ln1_g, ln1_b, dflag, nullptr, nullptr, QL, nullptr, nullptr);

  // 6. y2 = h1 W2 + b2 -> QH ; p2 = p1 + gelu(LN(y2)) (in-place hi/lo)
  gemm_bt<0><<<dim3(256, 8), 256, 0, stream>>>(QL, nullptr, nullptr, W2H, nullptr, nullptr,
      b2, dflag, 1, 0, nullptr, nullptr, nullptr, QH, nullptr, BN, D_DIM, D_DIM);
  ln_gelu<1><<<BN, 256, 0, stream>>>(QH, ln2_g, ln2_b, dflag, PH, PL, nullptr, PH, PL);

  // 7. BCIM
  bcim_dots<<<dim3(B_IMG, 8), 256, 0, stream>>>(PH, PL, G);
  bcim_sim_k<<<B_IMG, 256, 0, stream>>>(G, sim);
  bcim_scale<<<(BN * D_DIM / 4) / 256, 256, 0, stream>>>(PH, PL, sim, out);
}

// Round 4
// 1354.632 us; speedup vs baseline: 1.1558x; 1.0225x over previous
//
#include <hip/hip_runtime.h>
#include <math.h>

#define D_DIM 1024
#define M_DIM 256
#define B_IMG 64
#define N_TOK 512
#define BN    32768

typedef unsigned short u16;
typedef __attribute__((ext_vector_type(8))) __bf16 bf16x8;
typedef __attribute__((ext_vector_type(4))) float  f32x4;

__device__ __forceinline__ u16 f2bf(float f) {
  union { float f; unsigned u; } c; c.f = f;
  unsigned u = c.u;
  return (u16)((u + 0x7FFFu + ((u >> 16) & 1u)) >> 16);
}
__device__ __forceinline__ float bf2f(u16 h) {
  union { unsigned u; float f; } c; c.u = ((unsigned)h) << 16;
  return c.f;
}

// ---------------------------------------------------------------------------
// Input-dtype detector. flag: 0 = inputs are bf16, 1 = inputs are f32.
// ---------------------------------------------------------------------------
__global__ __launch_bounds__(64) void detect_dtype(const u16* __restrict__ p, int* __restrict__ dflag)
{
  const int lane = threadIdx.x;
  const float a = fabsf(bf2f(p[lane * 2]));
  const bool sane = (a >= 1e-20f && a <= 1e3f);
  const unsigned long long m = __ballot(sane);
  if (lane == 0) *dflag = (m == ~0ull) ? 0 : 1;
}

__device__ __forceinline__ float load_in(const void* p, size_t i, int f) {
  return f ? ((const float*)p)[i] : bf2f(((const u16*)p)[i]);
}

// ---------------------------------------------------------------------------
// 128x128 multi-pass GEMM — proven round-0 kernel (AV, S).
// EPI: 0 bf16, 1 f32, 2 res+hi/lo, 3 bf16 transposed, 4 hi/lo split.
// ---------------------------------------------------------------------------
template<int EPI>
__global__ __launch_bounds__(256) void gemm_bt(
    const u16* __restrict__ X0, const u16* __restrict__ X1, const u16* __restrict__ X2,
    const u16* __restrict__ Bt0, const u16* __restrict__ Bt1, const u16* __restrict__ Bt2,
    const void* __restrict__ bias, const int* __restrict__ dflag,
    int np_base, int np_extra,
    const u16* res_hi, const u16* res_lo,
    float* outf, u16* outb, u16* outb2,
    int R, int K, int NC)
{
  __shared__ u16 lA[128 * 64];
  __shared__ u16 lB[128 * 64];
  const int tid  = threadIdx.x;
  const int wave = tid >> 6, lane = tid & 63;
  const int quad = lane >> 4, l15 = lane & 15;
  const int wr = wave & 1, wc = wave >> 1;
  const int rblk = blockIdx.x, cblk = blockIdx.y;

  const int np = np_base + (np_extra ? np_extra * (*dflag) : 0);

  const int srow = lane >> 3;
  const int scol = ((lane & 7) ^ (srow & 7)) * 8;

  const u16* Xs[3] = {X0, X1, X2};
  const u16* Bs[3] = {Bt0, Bt1, Bt2};

  f32x4 acc[4][4] = {};

  for (int p = 0; p < np; ++p) {
    const u16* gA = Xs[p] + (size_t)(rblk * 128 + srow) * K + scol;
    const u16* gB = Bs[p] + (size_t)(cblk * 128 + srow) * K + scol;
    for (int k0 = 0; k0 < K; k0 += 64) {
#pragma unroll
      for (int i = 0; i < 4; ++i) {
        const int j = i * 4 + wave;
        __builtin_amdgcn_global_load_lds(
            (const __attribute__((address_space(1))) void*)(gA + (size_t)j * 8 * K + k0),
            (__attribute__((address_space(3))) void*)(lA + j * 512), 16, 0, 0);
        __builtin_amdgcn_global_load_lds(
            (const __attribute__((address_space(1))) void*)(gB + (size_t)j * 8 * K + k0),
            (__attribute__((address_space(3))) void*)(lB + j * 512), 16, 0, 0);
      }
      __syncthreads();
#pragma unroll
      for (int s = 0; s < 2; ++s) {
        bf16x8 af[4], bfr[4];
#pragma unroll
        for (int r = 0; r < 4; ++r) {
          const int row  = wr * 64 + r * 16 + l15;
          const int slot = (s * 4 + quad) ^ (row & 7);
          af[r] = *(const bf16x8*)(lA + row * 64 + slot * 8);
        }
#pragma unroll
        for (int c = 0; c < 4; ++c) {
          const int row  = wc * 64 + c * 16 + l15;
          const int slot = (s * 4 + quad) ^ (row & 7);
          bfr[c] = *(const bf16x8*)(lB + row * 64 + slot * 8);
        }
#pragma unroll
        for (int r = 0; r < 4; ++r)
#pragma unroll
          for (int c = 0; c < 4; ++c)
            acc[r][c] = __builtin_amdgcn_mfma_f32_16x16x32_bf16(af[r], bfr[c], acc[r][c], 0, 0, 0);
      }
      __syncthreads();
    }
  }

  const int fdt = bias ? *dflag : 0;
  const int crow0 = rblk * 128 + wr * 64;
  const int ccol0 = cblk * 128 + wc * 64;
#pragma unroll
  for (int c = 0; c < 4; ++c) {
    const int col = ccol0 + c * 16 + l15;
    const float bcol = bias ? load_in(bias, col, fdt) : 0.0f;
#pragma unroll
    for (int r = 0; r < 4; ++r) {
#pragma unroll
      for (int t = 0; t < 4; ++t) {
        const int row = crow0 + r * 16 + quad * 4 + t;
        const size_t idx = (size_t)row * NC + col;
        float v = acc[r][c][t] + bcol;
        if (EPI == 0) {
          outb[idx] = f2bf(v);
        } else if (EPI == 1) {
          outf[idx] = v;
        } else if (EPI == 2) {
          const float p = bf2f(res_hi[idx]) + bf2f(res_lo[idx]) + v;
          const u16 hi = f2bf(p);
          outb[idx]  = hi;
          outb2[idx] = f2bf(p - bf2f(hi));
        } else if (EPI == 3) {
          outb[(size_t)col * R + row] = f2bf(v);
        } else {  // EPI 4: hi/lo split
          const u16 hi = f2bf(v);
          outb[idx]  = hi;
          outb2[idx] = f2bf(v - bf2f(hi));
        }
      }
    }
  }
}

// ---------------------------------------------------------------------------
// Merged k+v projection: z=0 -> k = LN(o)W_k + b_k (hi/lo out kh/kl),
// z=1 -> vT = (LN(o)W_v + b_v)^T. 128^2 tile machinery. grid (2, 8, 2).
// ---------------------------------------------------------------------------
__global__ __launch_bounds__(256) void gemm_kv(
    const u16* __restrict__ on_h, const u16* __restrict__ on_l,
    const u16* __restrict__ WkH_, const u16* __restrict__ WkL_,
    const u16* __restrict__ WvH_, const u16* __restrict__ WvL_,
    const void* __restrict__ bk_, const void* __restrict__ bv_,
    const int* __restrict__ dflag,
    u16* __restrict__ kh, u16* __restrict__ kl, u16* __restrict__ vt)
{
  __shared__ u16 lA[128 * 64];
  __shared__ u16 lB[128 * 64];
  const int tid  = threadIdx.x;
  const int wave = tid >> 6, lane = tid & 63;
  const int quad = lane >> 4, l15 = lane & 15;
  const int wr = wave & 1, wc = wave >> 1;
  const int rblk = blockIdx.x, cblk = blockIdx.y;
  const int zv = blockIdx.z;
  const int K = D_DIM, NC = D_DIM, R = M_DIM;

  const int np = 2 + *dflag;

  const int srow = lane >> 3;
  const int scol = ((lane & 7) ^ (srow & 7)) * 8;

  const u16* Xs[3] = {on_h, on_l, on_h};
  const u16* Bs[3];
  if (zv == 0) { Bs[0] = WkH_; Bs[1] = WkH_; Bs[2] = WkL_; }
  else         { Bs[0] = WvH_; Bs[1] = WvH_; Bs[2] = WvL_; }
  const void* bias = zv == 0 ? bk_ : bv_;

  f32x4 acc[4][4] = {};

  for (int p = 0; p < np; ++p) {
    const u16* gA = Xs[p] + (size_t)(rblk * 128 + srow) * K + scol;
    const u16* gB = Bs[p] + (size_t)(cblk * 128 + srow) * K + scol;
    for (int k0 = 0; k0 < K; k0 += 64) {
#pragma unroll
      for (int i = 0; i < 4; ++i) {
        const int j = i * 4 + wave;
        __builtin_amdgcn_global_load_lds(
            (const __attribute__((address_space(1))) void*)(gA + (size_t)j * 8 * K + k0),
            (__attribute__((address_space(3))) void*)(lA + j * 512), 16, 0, 0);
        __builtin_amdgcn_global_load_lds(
            (const __attribute__((address_space(1))) void*)(gB + (size_t)j * 8 * K + k0),
            (__attribute__((address_space(3))) void*)(lB + j * 512), 16, 0, 0);
      }
      __syncthreads();
#pragma unroll
      for (int s = 0; s < 2; ++s) {
        bf16x8 af[4], bfr[4];
#pragma unroll
        for (int r = 0; r < 4; ++r) {
          const int row  = wr * 64 + r * 16 + l15;
          const int slot = (s * 4 + quad) ^ (row & 7);
          af[r] = *(const bf16x8*)(lA + row * 64 + slot * 8);
        }
#pragma unroll
        for (int c = 0; c < 4; ++c) {
          const int row  = wc * 64 + c * 16 + l15;
          const int slot = (s * 4 + quad) ^ (row & 7);
          bfr[c] = *(const bf16x8*)(lB + row * 64 + slot * 8);
        }
#pragma unroll
        for (int r = 0; r < 4; ++r)
#pragma unroll
          for (int c = 0; c < 4; ++c)
            acc[r][c] = __builtin_amdgcn_mfma_f32_16x16x32_bf16(af[r], bfr[c], acc[r][c], 0, 0, 0);
      }
      __syncthreads();
    }
  }

  const int fdt = *dflag;
  const int crow0 = rblk * 128 + wr * 64;
  const int ccol0 = cblk * 128 + wc * 64;
#pragma unroll
  for (int c = 0; c < 4; ++c) {
    const int col = ccol0 + c * 16 + l15;
    const float bcol = load_in(bias, col, fdt);
#pragma unroll
    for (int r = 0; r < 4; ++r) {
#pragma unroll
      for (int t = 0; t < 4; ++t) {
        const int row = crow0 + r * 16 + quad * 4 + t;
        float v = acc[r][c][t] + bcol;
        if (zv == 0) {
          const size_t idx = (size_t)row * NC + col;
          const u16 hi = f2bf(v);
          kh[idx] = hi;
          kl[idx] = f2bf(v - bf2f(hi));
        } else {
          vt[(size_t)col * R + row] = f2bf(v);
        }
      }
    }
  }
}

// ---------------------------------------------------------------------------
// 256x256-tile 8-wave GEMM, single-barrier counted-vmcnt pipeline:
// BK=32 K-tiles in a 4-slot LDS ring (4 x 32 KiB = 128 KiB), 3-deep
// prefetch. Per tile ONE barrier: {4 bfr ds_reads; stage(t+3) 4 gloads;
// setprio(1); for m=0..7 {af ds_read; 4 MFMA}; setprio(0); vmcnt(8);
// s_barrier}. The compiler schedules ds_read->MFMA with fine-grained
// lgkmcnt (m97 evidence) so LDS service overlaps MFMA; the counted
// vmcnt(8) confirms tile t+1 (its 4 loads were issued two full tiles
// earlier: FIFO = [t+1:4][t+2:4][t+3:4]). Correctness of the single
// barrier: each wave's LDS reads of tile t complete before its last MFMA
// (register deps), hence before the closing barrier; stage(t+3) writes
// slot (t-1)&3 whose reads were sealed by tile t-1's barrier; after every
// wave's own vmcnt(8) + barrier, ALL of tile t+1's data is in LDS.
// Tail stages clamp the source index (uniform control flow); dead clamped
// loads land in never-again-read slots and are drained by vmcnt(0) before
// exit. Grid (cblk, rblk) = (NC/256, R/256): A-panel-sharing blocks are
// launch-adjacent. LDS swizzle: phys slot = quad ^ ((row>>1)&3), inverse
// pre-applied on the per-lane global source (self-inverse XOR).
// EPI: 0 bf16, 1 f32, 2 res+hi/lo, 4 hi/lo split.
// Requires: R%256==0, NC%256==0, K%32==0 pow2 tiles, NT>=4.
// ---------------------------------------------------------------------------
template<int EPI>
__global__ __launch_bounds__(512, 2) void gemm256(
    const u16* __restrict__ X0, const u16* __restrict__ X1, const u16* __restrict__ X2,
    const u16* __restrict__ Bt0, const u16* __restrict__ Bt1, const u16* __restrict__ Bt2,
    const void* __restrict__ bias, const int* __restrict__ dflag,
    int np_base, int np_extra,
    const u16* res_hi, const u16* res_lo,
    float* outf, u16* outb, u16* outb2,
    int R, int K, int NC)
{
  extern __shared__ u16 lds2[];   // 4 slots x (A 256x32 | B 256x32) u16
  const int tid  = threadIdx.x;
  const int wave = tid >> 6, lane = tid & 63;
  const int quad = lane >> 4, l15 = lane & 15;
  const int wm = wave >> 2, wn = wave & 3;     // 2x4 wave grid
  const int rblk = blockIdx.y, cblk = blockIdx.x;

  const int np = np_base + (np_extra ? np_extra * (*dflag) : 0);
  const int ktiles = K >> 5;                    // BK=32 tiles per pass (pow2)
  const int ktl = 31 - __builtin_clz(ktiles);
  const int NT = np << ktl;

  const u16* Xs[3] = {X0, X1, X2};
  const u16* Bs[3] = {Bt0, Bt1, Bt2};

  // staging: one gload covers 16 rows x 4 slots (lane -> row lane>>2,
  // phys slot lane&3). Source col-group pre-swizzled (self-inverse).
  const int srow  = lane >> 2;
  const int sslot = lane & 3;

  f32x4 acc[8][4] = {};

  auto stage_tile = [&](int t) {
    const int tc = t < NT ? t : NT - 1;        // clamp (uniform tail)
    const int p  = tc >> ktl;
    const int k0 = (tc & (ktiles - 1)) << 5;
    u16* dst = lds2 + (t & 3) * 16384;         // 32 KiB slot (in u16)
#pragma unroll
    for (int i = 0; i < 2; ++i) {
      const int rbase = wave * 32 + i * 16;
      const int r  = rbase + srow;
      const int cg = (sslot ^ ((r >> 1) & 3)) * 8;
      __builtin_amdgcn_global_load_lds(
          (const __attribute__((address_space(1))) void*)(Xs[p] + (size_t)(rblk * 256 + r) * K + k0 + cg),
          (__attribute__((address_space(3))) void*)(dst + rbase * 32), 16, 0, 0);
    }
#pragma unroll
    for (int i = 0; i < 2; ++i) {
      const int rbase = wave * 32 + i * 16;
      const int r  = rbase + srow;
      const int cg = (sslot ^ ((r >> 1) & 3)) * 8;
      __builtin_amdgcn_global_load_lds(
          (const __attribute__((address_space(1))) void*)(Bs[p] + (size_t)(cblk * 256 + r) * K + k0 + cg),
          (__attribute__((address_space(3))) void*)(dst + 8192 + rbase * 32), 16, 0, 0);
    }
  };

  // prologue: tiles 0,1,2 staged (12 loads/wave); confirm tile 0 (vmcnt(8))
  stage_tile(0);
  stage_tile(1);
  stage_tile(2);
  asm volatile("s_waitcnt vmcnt(8)" ::: "memory");
  __builtin_amdgcn_s_barrier();

  for (int t = 0; t < NT; ++t) {
    const u16* bufA = lds2 + (t & 3) * 16384;
    const u16* bufB = bufA + 8192;
    bf16x8 bfr[4];
#pragma unroll
    for (int n = 0; n < 4; ++n) {
      const int row = wn * 64 + n * 16 + l15;
      const int ps  = quad ^ ((row >> 1) & 3);
      bfr[n] = *(const bf16x8*)(bufB + row * 32 + ps * 8);
    }
    stage_tile(t + 3);
    __builtin_amdgcn_s_setprio(1);
#pragma unroll
    for (int m = 0; m < 8; ++m) {
      const int row = wm * 128 + m * 16 + l15;
      const int ps  = quad ^ ((row >> 1) & 3);
      const bf16x8 a = *(const bf16x8*)(bufA + row * 32 + ps * 8);
#pragma unroll
      for (int n = 0; n < 4; ++n)
        acc[m][n] = __builtin_amdgcn_mfma_f32_16x16x32_bf16(a, bfr[n], acc[m][n], 0, 0, 0);
    }
    __builtin_amdgcn_s_setprio(0);
    // tile t+1's 4 loads (issued at tile t-2) must have landed; keep
    // t+2/t+3 (8 newest) in flight. Never drains to 0 in the loop.
    asm volatile("s_waitcnt vmcnt(8)" ::: "memory");
    __builtin_amdgcn_s_barrier();
  }
  // drain dead clamped prefetches before LDS is reused by the next block.
  asm volatile("s_waitcnt vmcnt(0)" ::: "memory");

  const int fdt = bias ? *dflag : 0;
  const int crow0 = rblk * 256 + wm * 128;
  const int ccol0 = cblk * 256 + wn * 64;
#pragma unroll
  for (int n = 0; n < 4; ++n) {
    const int col = ccol0 + n * 16 + l15;
    const float bcol = bias ? load_in(bias, col, fdt) : 0.0f;
#pragma unroll
    for (int m = 0; m < 8; ++m) {
#pragma unroll
      for (int u = 0; u < 4; ++u) {
        const int row = crow0 + m * 16 + quad * 4 + u;
        const size_t idx = (size_t)row * NC + col;
        float v = acc[m][n][u] + bcol;
        if (EPI == 0) {
          outb[idx] = f2bf(v);
        } else if (EPI == 1) {
          outf[idx] = v;
        } else if (EPI == 2) {
          const float pp = bf2f(res_hi[idx]) + bf2f(res_lo[idx]) + v;
          const u16 hi = f2bf(pp);
          outb[idx]  = hi;
          outb2[idx] = f2bf(pp - bf2f(hi));
        } else {  // EPI 4
          const u16 hi = f2bf(v);
          outb[idx]  = hi;
          outb2[idx] = f2bf(v - bf2f(hi));
        }
      }
    }
  }
}

// ---------------------------------------------------------------------------
// LayerNorm over D=1024 on raw input (dtype via flag); writes hi/lo bf16 pair.
// ---------------------------------------------------------------------------
__global__ __launch_bounds__(256) void ln_row(
    const void* __restrict__ x, const void* __restrict__ g, const void* __restrict__ b,
    const int* __restrict__ dflag, u16* __restrict__ oh, u16* __restrict__ ol)
{
  const int f = *dflag;
  const int row = blockIdx.x, tid = threadIdx.x;
  const int col = tid * 4;
  const size_t base = (size_t)row * 1024 + col;
  float v0, v1, v2, v3;
  if (f) {
    const float4 xv = *(const float4*)((const float*)x + base);
    v0 = xv.x; v1 = xv.y; v2 = xv.z; v3 = xv.w;
  } else {
    const ushort4 xv = *(const ushort4*)((const u16*)x + base);
    v0 = bf2f(xv.x); v1 = bf2f(xv.y); v2 = bf2f(xv.z); v3 = bf2f(xv.w);
  }
  float s  = v0 + v1 + v2 + v3;
  float sq = v0 * v0 + v1 * v1 + v2 * v2 + v3 * v3;
#pragma unroll
  for (int o = 32; o > 0; o >>= 1) { s += __shfl_xor(s, o); sq += __shfl_xor(sq, o); }
  __shared__ float red[8];
  if ((tid & 63) == 0) { red[tid >> 6] = s; red[4 + (tid >> 6)] = sq; }
  __syncthreads();
  s  = red[0] + red[1] + red[2] + red[3];
  sq = red[4] + red[5] + red[6] + red[7];
  const float mean = s * (1.0f / 1024.0f);
  const float var  = sq * (1.0f / 1024.0f) - mean * mean;
  const float rs   = rsqrtf(var + 1e-5f);
  float y[4];
  y[0] = (v0 - mean) * rs * load_in(g, col + 0, f) + load_in(b, col + 0, f);
  y[1] = (v1 - mean) * rs * load_in(g, col + 1, f) + load_in(b, col + 1, f);
  y[2] = (v2 - mean) * rs * load_in(g, col + 2, f) + load_in(b, col + 2, f);
  y[3] = (v3 - mean) * rs * load_in(g, col + 3, f) + load_in(b, col + 3, f);
  ushort4 hv, lv;
  hv.x = f2bf(y[0]); lv.x = f2bf(y[0] - bf2f(hv.x));
  hv.y = f2bf(y[1]); lv.y = f2bf(y[1] - bf2f(hv.y));
  hv.z = f2bf(y[2]); lv.z = f2bf(y[2] - bf2f(hv.z));
  hv.w = f2bf(y[3]); lv.w = f2bf(y[3] - bf2f(hv.w));
  *(ushort4*)(oh + base) = hv;
  *(ushort4*)(ol + base) = lv;
}

// ---------------------------------------------------------------------------
// LN + exact GELU on internal bf16 input; g/b raw dtype.
// MODE 0: write gelu bf16 (ob). MODE 1: p = res_hi+res_lo + gelu, hi/lo out.
// ---------------------------------------------------------------------------
template<int MODE>
__global__ __launch_bounds__(256) void ln_gelu(
    const u16* __restrict__ x, const void* __restrict__ g, const void* __restrict__ b,
    const int* __restrict__ dflag,
    const u16* res_hi, const u16* res_lo,
    u16* ob, u16* oh, u16* ol)
{
  const int f = *dflag;
  const int row = blockIdx.x, tid = threadIdx.x;
  const int col = tid * 4;
  const size_t base = (size_t)row * 1024 + col;
  const ushort4 xv = *(const ushort4*)(x + base);
  const float v0 = bf2f(xv.x), v1 = bf2f(xv.y), v2 = bf2f(xv.z), v3 = bf2f(xv.w);
  float s  = v0 + v1 + v2 + v3;
  float sq = v0 * v0 + v1 * v1 + v2 * v2 + v3 * v3;
#pragma unroll
  for (int o = 32; o > 0; o >>= 1) { s += __shfl_xor(s, o); sq += __shfl_xor(sq, o); }
  __shared__ float red[8];
  if ((tid & 63) == 0) { red[tid >> 6] = s; red[4 + (tid >> 6)] = sq; }
  __syncthreads();
  s  = red[0] + red[1] + red[2] + red[3];
  sq = red[4] + red[5] + red[6] + red[7];
  const float mean = s * (1.0f / 1024.0f);
  const float var  = sq * (1.0f / 1024.0f) - mean * mean;
  const float rs   = rsqrtf(var + 1e-5f);
  float z[4], h[4];
  z[0] = (v0 - mean) * rs * load_in(g, col + 0, f) + load_in(b, col + 0, f);
  z[1] = (v1 - mean) * rs * load_in(g, col + 1, f) + load_in(b, col + 1, f);
  z[2] = (v2 - mean) * rs * load_in(g, col + 2, f) + load_in(b, col + 2, f);
  z[3] = (v3 - mean) * rs * load_in(g, col + 3, f) + load_in(b, col + 3, f);
#pragma unroll
  for (int i = 0; i < 4; ++i)
    h[i] = 0.5f * z[i] * (1.0f + erff(z[i] * 0.70710678118654752f));
  if (MODE == 0) {
    *(ushort4*)(ob + base) = make_ushort4(f2bf(h[0]), f2bf(h[1]), f2bf(h[2]), f2bf(h[3]));
  } else {
    const ushort4 rh = *(const ushort4*)(res_hi + base);
    const ushort4 rl = *(const ushort4*)(res_lo + base);
    float p[4];
    p[0] = bf2f(rh.x) + bf2f(rl.x) + h[0];
    p[1] = bf2f(rh.y) + bf2f(rl.y) + h[1];
    p[2] = bf2f(rh.z) + bf2f(rl.z) + h[2];
    p[3] = bf2f(rh.w) + bf2f(rl.w) + h[3];
    ushort4 hv, lv;
    hv.x = f2bf(p[0]); lv.x = f2bf(p[0] - bf2f(hv.x));
    hv.y = f2bf(p[1]); lv.y = f2bf(p[1] - bf2f(hv.y));
    hv.z = f2bf(p[2]); lv.z = f2bf(p[2] - bf2f(hv.z));
    hv.w = f2bf(p[3]); lv.w = f2bf(p[3] - bf2f(hv.w));
    *(ushort4*)(oh + base) = hv;
    *(ushort4*)(ol + base) = lv;
  }
}

// ---------------------------------------------------------------------------
// Softmax over M=256; one wave per row, 4 rows per block. f32 in, bf16 out.
// ---------------------------------------------------------------------------
__global__ __launch_bounds__(256) void softmax256(const float* __restrict__ S, u16* __restrict__ A)
{
  const int tid = threadIdx.x, lane = tid & 63, wave = tid >> 6;
  const size_t row = (size_t)blockIdx.x * 4 + wave;
  const float4 v = *(const float4*)(S + row * 256 + lane * 4);
  float m = fmaxf(fmaxf(v.x, v.y), fmaxf(v.z, v.w));
#pragma unroll
  for (int o = 32; o > 0; o >>= 1) m = fmaxf(m, __shfl_xor(m, o));
  const float e0 = expf(v.x - m), e1 = expf(v.y - m), e2 = expf(v.z - m), e3 = expf(v.w - m);
  float s = e0 + e1 + e2 + e3;
#pragma unroll
  for (int o = 32; o > 0; o >>= 1) s += __shfl_xor(s, o);
  const float r = 1.0f / s;
  *(ushort4*)(A + row * 256 + lane * 4) =
      make_ushort4(f2bf(e0 * r), f2bf(e1 * r), f2bf(e2 * r), f2bf(e3 * r));
}

// ---------------------------------------------------------------------------
// Weight transpose->bf16 hi/lo from raw dtype: Wt[n][k] = W[k][n], 5 matrices.
// ---------------------------------------------------------------------------
__global__ __launch_bounds__(256) void wtrans5(
    const void* w0, const void* w1, const void* w2, const void* w3, const void* w4,
    u16* h0, u16* h1, u16* h2, u16* h3, u16* h4,
    u16* l0, u16* l1, u16* l2, u16* l3, u16* l4,
    const int* __restrict__ dflag)
{
  const int f = *dflag;
  const void* W; u16* H; u16* L;
  switch (blockIdx.z) {
    case 0: W = w0; H = h0; L = l0; break;
    case 1: W = w1; H = h1; L = l1; break;
    case 2: W = w2; H = h2; L = l2; break;
    case 3: W = w3; H = h3; L = l3; break;
    default: W = w4; H = h4; L = l4; break;
  }
  __shared__ u16 th[32][33];
  __shared__ u16 tl[32][33];
  const int tx = threadIdx.x & 31, ty = threadIdx.x >> 5;
  const int bx = blockIdx.x, by = blockIdx.y;
#pragma unroll
  for (int i = 0; i < 4; ++i) {
    const int r = ty + i * 8;
    const float v = load_in(W, ((size_t)by * 32 + r) * 1024 + bx * 32 + tx, f);
    const u16 hi = f2bf(v);
    th[r][tx] = hi;
    tl[r][tx] = f2bf(v - bf2f(hi));
  }
  __syncthreads();
#pragma unroll
  for (int i = 0; i < 4; ++i) {
    const int r = ty + i * 8;
    const size_t o = ((size_t)bx * 32 + r) * 1024 + by * 32 + tx;
    H[o] = th[tx][r];
    L[o] = tl[tx][r];
  }
}

__global__ __launch_bounds__(256) void zerof(float* p, int n)
{
  const int i = blockIdx.x * 256 + threadIdx.x;
  if (i < n) p[i] = 0.0f;
}

// ---------------------------------------------------------------------------
// BCIM phase 1: 9-offset Gram band on p2 = hi+lo. grid = (B, 8 d-splits).
// ---------------------------------------------------------------------------
__global__ __launch_bounds__(256) void bcim_dots(
    const u16* __restrict__ p2h, const u16* __restrict__ p2l, float* __restrict__ G)
{
  const int b = blockIdx.x, ds = blockIdx.y;
  __shared__ float T[512][17];
  float acc[9] = {0, 0, 0, 0, 0, 0, 0, 0, 0};
  const int tid = threadIdx.x;
  const int px = tid & 15, py = tid >> 4;
  for (int ch = 0; ch < 8; ++ch) {
    const int d0 = ds * 128 + ch * 16;
#pragma unroll
    for (int i = 0; i < 8; ++i) {
      const int j = i * 256 + tid;
      const int r = j >> 2, q4 = j & 3;
      const size_t base = ((size_t)b * 512 + r) * 1024 + d0 + q4 * 4;
      const ushort4 hv = *(const ushort4*)(p2h + base);
      const ushort4 lv = *(const ushort4*)(p2l + base);
      T[r][q4 * 4 + 0] = bf2f(hv.x) + bf2f(lv.x);
      T[r][q4 * 4 + 1] = bf2f(hv.y) + bf2f(lv.y);
      T[r][q4 * 4 + 2] = bf2f(hv.z) + bf2f(lv.z);
      T[r][q4 * 4 + 3] = bf2f(hv.w) + bf2f(lv.w);
    }
    __syncthreads();
    float a0[16], a1[16];
#pragma unroll
    for (int dc = 0; dc < 16; ++dc) { a0[dc] = T[tid][dc]; a1[dc] = T[tid + 256][dc]; }
#pragma unroll
    for (int o = 0; o < 9; ++o) {
      const int dy = o / 3 - 1, dx = o % 3 - 1;
      const int qx = px + dx, qy = py + dy;
      if (qx >= 0 && qx < 16 && qy >= 0 && qy < 16) {
        const int qp = qy * 16 + qx;
        float sum = 0.0f;
#pragma unroll
        for (int dc = 0; dc < 16; ++dc)
          sum += a0[dc] * T[qp][dc] + a1[dc] * T[qp + 256][dc];
        acc[o] += sum;
      }
    }
    __syncthreads();
  }
#pragma unroll
  for (int o = 0; o < 9; ++o)
    atomicAdd(&G[((size_t)b * 9 + o) * 256 + tid], acc[o]);
}

// BCIM phase 2: sim[b][pix]
__global__ __launch_bounds__(256) void bcim_sim_k(const float* __restrict__ G, float* __restrict__ sim)
{
  const int b = blockIdx.x, tid = threadIdx.x;
  __shared__ float nrm[256];
  const float nv = sqrtf(G[((size_t)b * 9 + 4) * 256 + tid]);
  nrm[tid] = nv;
  __syncthreads();
  const int px = tid & 15, py = tid >> 4;
  float s = 0.0f;
#pragma unroll
  for (int o = 0; o < 9; ++o) {
    const int dy = o / 3 - 1, dx = o % 3 - 1;
    const int qx = px + dx, qy = py + dy;
    if (qx >= 0 && qx < 16 && qy >= 0 && qy < 16)
      s += G[((size_t)b * 9 + o) * 256 + tid] / (nv * nrm[qy * 16 + qx]);
  }
  sim[b * 256 + tid] = s * (1.0f / 9.0f);
}

// BCIM phase 3: out[b,n,d] = (p2h+p2l)[b,n,d] * sim[b][n&255]  (f32 out)
__global__ __launch_bounds__(256) void bcim_scale(
    const u16* __restrict__ p2h, const u16* __restrict__ p2l,
    const float* __restrict__ sim, float* __restrict__ out)
{
  const size_t i4 = (size_t)blockIdx.x * 256 + threadIdx.x;
  const size_t base = i4 * 4;
  const ushort4 hv = *(const ushort4*)(p2h + base);
  const ushort4 lv = *(const ushort4*)(p2l + base);
  const size_t n = base >> 10;
  const size_t b = n >> 9;
  const int pix = (int)(n & 255);
  const float s = sim[b * 256 + pix];
  *(float4*)(out + base) = make_float4(
      (bf2f(hv.x) + bf2f(lv.x)) * s, (bf2f(hv.y) + bf2f(lv.y)) * s,
      (bf2f(hv.z) + bf2f(lv.z)) * s, (bf2f(hv.w) + bf2f(lv.w)) * s);
}

// ---------------------------------------------------------------------------
extern "C" void kernel_launch(void* const* d_in, const int* in_sizes, int n_in,
                              void* d_out, int out_size, void* d_ws, size_t ws_size,
                              hipStream_t stream)
{
  (void)in_sizes; (void)n_in; (void)out_size; (void)ws_size;
  const void* p_vector      = d_in[0];
  const void* object_vector = d_in[1];
  const void* ln_p_g = d_in[2];
  const void* ln_p_b = d_in[3];
  const void* ln_o_g = d_in[4];
  const void* ln_o_b = d_in[5];
  const void* Wq = d_in[6];  const void* bq = d_in[7];
  const void* Wk = d_in[8];  const void* bk = d_in[9];
  const void* Wv = d_in[10]; const void* bv = d_in[11];
  const void* W1 = d_in[12]; const void* b1 = d_in[13];
  const void* ln1_g = d_in[14]; const void* ln1_b = d_in[15];
  const void* W2 = d_in[16]; const void* b2 = d_in[17];
  const void* ln2_g = d_in[18]; const void* ln2_b = d_in[19];
  float* out = (float*)d_out;

  char* ws = (char*)d_ws;
  size_t off = 0;
  auto alloc = [&](size_t bytes) -> void* {
    void* p = ws + off;
    off += (bytes + 255) & ~(size_t)255;
    return p;
  };
  int* dflag = (int*)alloc(256);
  u16* WqH = (u16*)alloc((size_t)D_DIM * D_DIM * 2);
  u16* WkH = (u16*)alloc((size_t)D_DIM * D_DIM * 2);
  u16* WvH = (u16*)alloc((size_t)D_DIM * D_DIM * 2);
  u16* W1H = (u16*)alloc((size_t)D_DIM * D_DIM * 2);
  u16* W2H = (u16*)alloc((size_t)D_DIM * D_DIM * 2);
  u16* WqL = (u16*)alloc((size_t)D_DIM * D_DIM * 2);
  u16* WkL = (u16*)alloc((size_t)D_DIM * D_DIM * 2);
  u16* WvL = (u16*)alloc((size_t)D_DIM * D_DIM * 2);
  u16* W1L = (u16*)alloc((size_t)D_DIM * D_DIM * 2);
  u16* W2L = (u16*)alloc((size_t)D_DIM * D_DIM * 2);
  u16* PH = (u16*)alloc((size_t)BN * D_DIM * 2);   // pn_hi -> p1_hi -> p2_hi
  u16* PL = (u16*)alloc((size_t)BN * D_DIM * 2);   // pn_lo -> p1_lo -> p2_lo
  u16* QH = (u16*)alloc((size_t)BN * D_DIM * 2);   // q_hi -> y1 -> y2
  u16* QL = (u16*)alloc((size_t)BN * D_DIM * 2);   // q_lo -> h1
  float* S_f = (float*)alloc((size_t)BN * M_DIM * 4);
  u16* A_b   = (u16*)alloc((size_t)BN * M_DIM * 2);
  u16* onH = (u16*)alloc((size_t)M_DIM * D_DIM * 2);
  u16* onL = (u16*)alloc((size_t)M_DIM * D_DIM * 2);
  u16* kH  = (u16*)alloc((size_t)M_DIM * D_DIM * 2);
  u16* kL  = (u16*)alloc((size_t)M_DIM * D_DIM * 2);
  u16* vT  = (u16*)alloc((size_t)D_DIM * M_DIM * 2);
  float* G   = (float*)alloc((size_t)B_IMG * 9 * 256 * 4);
  float* sim = (float*)alloc((size_t)B_IMG * 256 * 4);

  // 0. dtype detect, weight transposes (hi/lo), zero G
  detect_dtype<<<1, 64, 0, stream>>>((const u16*)p_vector, dflag);
  wtrans5<<<dim3(32, 32, 5), 256, 0, stream>>>(Wq, Wk, Wv, W1, W2,
      WqH, WkH, WvH, W1H, W2H, WqL, WkL, WvL, W1L, W2L, dflag);
  zerof<<<(B_IMG * 9 * 256 + 255) / 256, 256, 0, stream>>>(G, B_IMG * 9 * 256);

  // 1. LayerNorms -> hi/lo pairs
  ln_row<<<BN, 256, 0, stream>>>(p_vector, ln_p_g, ln_p_b, dflag, PH, PL);
  ln_row<<<M_DIM, 256, 0, stream>>>(object_vector, ln_o_g, ln_o_b, dflag, onH, onL);

  // 2. k+v merged; q on single-barrier gemm256 pipeline
  gemm_kv<<<dim3(2, 8, 2), 256, 0, stream>>>(onH, onL, WkH, WkL, WvH, WvL,
      bk, bv, dflag, kH, kL, vT);
  gemm256<4><<<dim3(4, 128), 512, 131072, stream>>>(PH, PL, PH, WqH, WqH, WqL,
      bq, dflag, 2, 1, nullptr, nullptr, nullptr, QH, QL, BN, D_DIM, D_DIM);

  // 3. S = (q_hi+q_lo)(k_hi+k_lo)^T (3 split passes); softmax -> A bf16
  gemm_bt<1><<<dim3(256, 2), 256, 0, stream>>>(QH, QL, QH, kH, kH, kL,
      nullptr, dflag, 3, 0, nullptr, nullptr, S_f, nullptr, nullptr, BN, D_DIM, M_DIM);
  softmax256<<<BN / 4, 256, 0, stream>>>(S_f, A_b);

  // 4. p1 = pn + A v  (in-place hi/lo over PH/PL)
  gemm_bt<2><<<dim3(256, 8), 256, 0, stream>>>(A_b, nullptr, nullptr, vT, nullptr, nullptr,
      nullptr, dflag, 1, 0, PH, PL, nullptr, PH, PL, BN, M_DIM, D_DIM);

  // 5. y1 = p1_hi W1 + b1 -> QH ; h1 = gelu(LN(y1)) -> QL
  gemm256<0><<<dim3(4, 128), 512, 131072, stream>>>(PH, nullptr, nullptr, W1H, nullptr, nullptr,
      b1, dflag, 1, 0, nullptr, nullptr, nullptr, QH, nullptr, BN, D_DIM, D_DIM);
  ln_gelu<0><<<BN, 256, 0, stream>>>(QH, ln1_g, ln1_b, dflag, nullptr, nullptr, QL, nullptr, nullptr);

  // 6. y2 = h1 W2 + b2 -> QH ; p2 = p1 + gelu(LN(y2)) (in-place hi/lo)
  gemm256<0><<<dim3(4, 128), 512, 131072, stream>>>(QL, nullptr, nullptr, W2H, nullptr, nullptr,
      b2, dflag, 1, 0, nullptr, nullptr, nullptr, QH, nullptr, BN, D_DIM, D_DIM);
  ln_gelu<1><<<BN, 256, 0, stream>>>(QH, ln2_g, ln2_b, dflag, PH, PL, nullptr, PH, PL);

  // 7. BCIM
  bcim_dots<<<dim3(B_IMG, 8), 256, 0, stream>>>(PH, PL, G);
  bcim_sim_k<<<B_IMG, 256, 0, stream>>>(G, sim);
  bcim_scale<<<(BN * D_DIM / 4) / 256, 256, 0, stream>>>(PH, PL, sim, out);
}